// Round 11
// baseline (381.654 us; speedup 1.0000x reference)
//
#include <hip/hip_runtime.h>

#define NODES 100000
#define EDGES 1600000
#define BSH 8
#define NBUCK ((NODES + 255) >> BSH)   // 391
#define CHUNK 4096
#define LMAX 8192
#define NCH64 ((NODES + 63) / 64)      // 1563 (tail clamped)
#define NCH32 ((NODES + 31) / 32)      // 3125
#define CONVB 12500                    // blocks for conv part of conv_hist
#define MLPGRID 512                    // 2 blocks/CU (LDS = 80 KB exactly)
// IN_F = HID_F = 128, OUT_F = 64

using bf16x8 = __attribute__((ext_vector_type(8))) short;
using f32x4  = __attribute__((ext_vector_type(4))) float;
using f32x2  = __attribute__((ext_vector_type(2))) float;

__device__ __forceinline__ unsigned short f2b(float f) {
    unsigned u = __builtin_bit_cast(unsigned, f);
    unsigned r = (u + 0x7FFFu + ((u >> 16) & 1u)) >> 16;
    return (unsigned short)r;
}

// ---- packed f32 helpers (CDNA VOP3P; dual-pump FP32) ----
__device__ __forceinline__ f32x2 pkadd(f32x2 a, f32x2 b) {
    f32x2 d;
    asm("v_pk_add_f32 %0, %1, %2" : "=v"(d) : "v"(a), "v"(b));
    return d;
}
__device__ __forceinline__ f32x2 pkfma(f32x2 a, f32x2 b, f32x2 c) {
    f32x2 d;
    asm("v_pk_fma_f32 %0, %1, %2, %3" : "=v"(d) : "v"(a), "v"(b), "v"(c));
    return d;
}
__device__ __forceinline__ unsigned cvt2bf(float lo, float hi) {
    unsigned r;
    asm("v_cvt_pk_bf16_f32 %0, %1, %2" : "=v"(r) : "v"(lo), "v"(hi));
    return r;
}

// pinned 16B global load (volatile: cannot be sunk/rematerialized)
__device__ __forceinline__ bf16x8 gl16(const unsigned short* p) {
    bf16x8 r;
    asm volatile("global_load_dwordx4 %0, %1, off" : "=&v"(r) : "v"(p));
    return r;
}

// unpack 8 fp8 (uint2) and accumulate into 4 packed-f32 accumulators
__device__ __forceinline__ void addpk8(f32x2* a, uint2 v) {
    a[0] = pkadd(a[0], __builtin_amdgcn_cvt_pk_f32_fp8((int)v.x, false));
    a[1] = pkadd(a[1], __builtin_amdgcn_cvt_pk_f32_fp8((int)v.x, true));
    a[2] = pkadd(a[2], __builtin_amdgcn_cvt_pk_f32_fp8((int)v.y, false));
    a[3] = pkadd(a[3], __builtin_amdgcn_cvt_pk_f32_fp8((int)v.y, true));
}

// ---------------- fused conversions + coarse histogram ----------------

__global__ __launch_bounds__(256) void conv_hist(
    const float* __restrict__ in, unsigned short* __restrict__ outb,
    unsigned char* __restrict__ outq, int n4,
    const float* __restrict__ W1s, const float* __restrict__ W1n,
    const float* __restrict__ W2s, const float* __restrict__ W2n,
    unsigned short* __restrict__ Wt1s, unsigned short* __restrict__ Wt1n,
    unsigned short* __restrict__ Wt2s, unsigned short* __restrict__ Wt2n,
    const int* __restrict__ dst, int* __restrict__ bucket_cnt) {
    int t = threadIdx.x;
    if (blockIdx.x < CONVB) {
        int i = blockIdx.x * 256 + t;
        if (i < n4) {
            float4 v = reinterpret_cast<const float4*>(in)[i];
            uint2 o;
            o.x = (unsigned)f2b(v.x) | ((unsigned)f2b(v.y) << 16);
            o.y = (unsigned)f2b(v.z) | ((unsigned)f2b(v.w) << 16);
            reinterpret_cast<uint2*>(outb)[i] = o;
            int pk = __builtin_amdgcn_cvt_pk_fp8_f32(v.x, v.y, 0, false);
            pk = __builtin_amdgcn_cvt_pk_fp8_f32(v.z, v.w, pk, true);
            reinterpret_cast<unsigned*>(outq)[i] = (unsigned)pk;
        }
        if (i < 16384) {
            int k = i >> 7, n = i & 127;
            Wt1s[n * 128 + k] = f2b(W1s[i]);
            Wt1n[n * 128 + k] = f2b(W1n[i]);
        }
        if (i < 8192) {
            int k = i >> 6, n = i & 63;
            Wt2s[n * 128 + k] = f2b(W2s[i]);
            Wt2n[n * 128 + k] = f2b(W2n[i]);
        }
        return;
    }
    // ---- bhist part ----
    __shared__ int lcnt[512];
    lcnt[t] = 0; lcnt[t + 256] = 0;
    __syncthreads();
    int base = (blockIdx.x - CONVB) * 16384;
    int n = EDGES - base;
    if (n > 16384) n = 16384;
    const int4* d4 = reinterpret_cast<const int4*>(dst + base);
    for (int i = t; i < (n >> 2); i += 256) {
        int4 d = d4[i];
        atomicAdd(&lcnt[d.x >> BSH], 1);
        atomicAdd(&lcnt[d.y >> BSH], 1);
        atomicAdd(&lcnt[d.z >> BSH], 1);
        atomicAdd(&lcnt[d.w >> BSH], 1);
    }
    for (int i = (n & ~3) + t; i < n; i += 256) atomicAdd(&lcnt[dst[base + i] >> BSH], 1);
    __syncthreads();
    if (lcnt[t]) atomicAdd(&bucket_cnt[t], lcnt[t]);
    if (lcnt[t + 256]) atomicAdd(&bucket_cnt[t + 256], lcnt[t + 256]);
}

__global__ void bscan_kernel(const int* __restrict__ bucket_cnt, int* __restrict__ bucket_off,
                             int* __restrict__ gcursor, int* __restrict__ row_ptr) {
    __shared__ int sh[512];
    int t = threadIdx.x;
    int v = (t < NBUCK) ? bucket_cnt[t] : 0;
    sh[t] = v;
    __syncthreads();
    for (int off = 1; off < 512; off <<= 1) {
        int x = (t >= off) ? sh[t - off] : 0;
        __syncthreads();
        sh[t] += x;
        __syncthreads();
    }
    int excl = sh[t] - v;
    if (t < NBUCK) { bucket_off[t] = excl; gcursor[t] = excl; }
    if (t == NBUCK) bucket_off[t] = EDGES;
    if (t == 0) row_ptr[NODES] = EDGES;
}

// Bin edges by coarse bucket; write packed (dst&255)<<24|src runs.
__global__ __launch_bounds__(256) void binscat_kernel(
    const int* __restrict__ src, const int* __restrict__ dst,
    int* __restrict__ gcursor, unsigned* __restrict__ pairs) {
    __shared__ int cnt[512];
    __shared__ int scn[512];
    __shared__ int gbs[512];
    __shared__ int cur[512];
    __shared__ uint2 stage[CHUNK];
    int t = threadIdx.x;
    int base = blockIdx.x * CHUNK;
    int n = EDGES - base;
    if (n > CHUNK) n = CHUNK;

    cnt[t] = 0; cnt[t + 256] = 0;
    __syncthreads();

    uint2 my[16];
#pragma unroll
    for (int i = 0; i < 16; ++i) {
        int idx = t + i * 256;
        if (idx < n) {
            int d = dst[base + idx];
            int s = src[base + idx];
            my[i] = make_uint2((unsigned)d, (unsigned)s);
            atomicAdd(&cnt[d >> BSH], 1);
        } else {
            my[i] = make_uint2(0xFFFFFFFFu, 0);
        }
    }
    __syncthreads();
    scn[t] = cnt[t]; scn[t + 256] = cnt[t + 256];
    __syncthreads();
    for (int off = 1; off < 512; off <<= 1) {
        int a0 = (t >= off) ? scn[t - off] : 0;
        int a1 = (t + 256 >= off) ? scn[t + 256 - off] : 0;
        __syncthreads();
        scn[t] += a0; scn[t + 256] += a1;
        __syncthreads();
    }
    cur[t] = scn[t] - cnt[t];
    cur[t + 256] = scn[t + 256] - cnt[t + 256];
    __syncthreads();
#pragma unroll
    for (int i = 0; i < 16; ++i) {
        if (my[i].x != 0xFFFFFFFFu) {
            int b = (int)(my[i].x >> BSH);
            int p = atomicAdd(&cur[b], 1);
            stage[p] = my[i];
        }
    }
    for (int b2 = t; b2 < 512; b2 += 256) {
        int c = cnt[b2];
        gbs[b2] = (c > 0 && b2 < NBUCK) ? atomicAdd(&gcursor[b2], c) : 0;
    }
    __syncthreads();
    for (int idx = t; idx < n; idx += 256) {
        uint2 p = stage[idx];
        int b = (int)(p.x >> BSH);
        int excl = scn[b] - cnt[b];
        pairs[gbs[b] + idx - excl] = ((p.x & 255u) << 24) | p.y;
    }
}

__global__ __launch_bounds__(256) void localsort_kernel(
    const unsigned* __restrict__ pairs, const int* __restrict__ bucket_off,
    int* __restrict__ row_ptr, int* __restrict__ src_sorted) {
    __shared__ int cnt[256];
    __shared__ int cur[256];
    __shared__ int stage[LMAX];
    int b = blockIdx.x;
    int t = threadIdx.x;
    int node0 = b << BSH;
    int pbeg = bucket_off[b], pend = bucket_off[b + 1];
    int n = pend - pbeg;
    cnt[t] = 0;
    __syncthreads();
    for (int e = pbeg + t; e < pend; e += 256)
        atomicAdd(&cnt[(int)(pairs[e] >> 24)], 1);
    __syncthreads();
    int v = cnt[t];
    cur[t] = v;
    __syncthreads();
    for (int off = 1; off < 256; off <<= 1) {
        int x = (t >= off) ? cur[t - off] : 0;
        __syncthreads();
        cur[t] += x;
        __syncthreads();
    }
    int excl = cur[t] - v;
    int node = node0 + t;
    if (node < NODES) row_ptr[node] = pbeg + excl;
    cur[t] = excl;
    __syncthreads();
    if (n <= LMAX) {
        for (int e = pbeg + t; e < pend; e += 256) {
            unsigned p = pairs[e];
            int pos = atomicAdd(&cur[(int)(p >> 24)], 1);
            stage[pos] = (int)(p & 0xFFFFFFu);
        }
        __syncthreads();
        for (int i = t; i < n; i += 256) src_sorted[pbeg + i] = stage[i];
    } else {
        for (int e = pbeg + t; e < pend; e += 256) {
            unsigned p = pairs[e];
            int pos = atomicAdd(&cur[(int)(p >> 24)], 1);
            src_sorted[pbeg + pos] = (int)(p & 0xFFFFFFu);
        }
    }
}

// ---------------- Mean aggregation, fp8 gather ----------------
// v5: XCD-sliced, lane-per-edge. slice = blockIdx&7 -> XCD (round-robin
// dispatch), so each XCD gathers only its 16-byte column slice of the fp8
// table: 1.6 MB working set, L2-resident (vs 12.8 MB -> 81 MB LLC traffic).
// Each 8-lane group owns one node; lane sl processes edges beg+sl, +8, ...
// directly (each edge counted ONCE — v4's shfl-broadcast made all 8 lanes
// accumulate all edges, 8x overcount). Unroll-2: 2 gathers/lane = 16/group
// in flight. 3-hop shfl_xor reduce; lanes 0,1 write 16B each.

__global__ __launch_bounds__(256) void agg128_fp8(
    const unsigned char* __restrict__ xq, const int* __restrict__ row_ptr,
    const int* __restrict__ srcs, unsigned short* __restrict__ out) {
    int bid = blockIdx.x;
    int s = bid & 7;                  // feature slice == XCD
    int chunk = bid >> 3;             // 32 nodes per block
    int lane = threadIdx.x & 63;
    int sl = lane & 7;
    int n = chunk * 32 + ((int)(threadIdx.x >> 6)) * 8 + (lane >> 3);
    if (n >= NODES) return;
    int beg = row_ptr[n], end = row_ptr[n + 1];

    f32x2 A0[4], A1[4], B0[4], B1[4];
#pragma unroll
    for (int i = 0; i < 4; ++i) {
        A0[i] = {0.f, 0.f}; A1[i] = {0.f, 0.f};
        B0[i] = {0.f, 0.f}; B1[i] = {0.f, 0.f};
    }

    const unsigned char* xs = xq + s * 16;
    int e = beg + sl;
    for (; e + 8 < end; e += 16) {
        int s0 = srcs[e];
        int s1 = srcs[e + 8];
        uint4 v0 = *reinterpret_cast<const uint4*>(xs + (size_t)s0 * 128);
        uint4 v1 = *reinterpret_cast<const uint4*>(xs + (size_t)s1 * 128);
        addpk8(A0, make_uint2(v0.x, v0.y));
        addpk8(A1, make_uint2(v0.z, v0.w));
        addpk8(B0, make_uint2(v1.x, v1.y));
        addpk8(B1, make_uint2(v1.z, v1.w));
    }
    if (e < end) {
        int s0 = srcs[e];
        uint4 v0 = *reinterpret_cast<const uint4*>(xs + (size_t)s0 * 128);
        addpk8(A0, make_uint2(v0.x, v0.y));
        addpk8(A1, make_uint2(v0.z, v0.w));
    }

#pragma unroll
    for (int i = 0; i < 4; ++i) {
        A0[i] = pkadd(A0[i], B0[i]);
        A1[i] = pkadd(A1[i], B1[i]);
    }
    // reduce across the 8 lanes of the group (xor 1,2,4)
#pragma unroll
    for (int i = 0; i < 4; ++i) {
        f32x2 t;
#pragma unroll
        for (int h = 1; h <= 4; h <<= 1) {
            t[0] = __shfl_xor(A0[i][0], h, 64);
            t[1] = __shfl_xor(A0[i][1], h, 64);
            A0[i] = pkadd(A0[i], t);
            t[0] = __shfl_xor(A1[i][0], h, 64);
            t[1] = __shfl_xor(A1[i][1], h, 64);
            A1[i] = pkadd(A1[i], t);
        }
    }

    float inv = 1.0f / fmaxf((float)(end - beg), 1.0f);
    unsigned short* op = out + (size_t)n * 128 + s * 16;
    if (sl == 0) {
        uint4 o0;
        o0.x = cvt2bf(A0[0][0] * inv, A0[0][1] * inv);
        o0.y = cvt2bf(A0[1][0] * inv, A0[1][1] * inv);
        o0.z = cvt2bf(A0[2][0] * inv, A0[2][1] * inv);
        o0.w = cvt2bf(A0[3][0] * inv, A0[3][1] * inv);
        *reinterpret_cast<uint4*>(op) = o0;
    } else if (sl == 1) {
        uint4 o1;
        o1.x = cvt2bf(A1[0][0] * inv, A1[0][1] * inv);
        o1.y = cvt2bf(A1[1][0] * inv, A1[1][1] * inv);
        o1.z = cvt2bf(A1[2][0] * inv, A1[2][1] * inv);
        o1.w = cvt2bf(A1[3][0] * inv, A1[3][1] * inv);
        *reinterpret_cast<uint4*>(op + 8) = o1;
    }
}

// agg64: group-per-node, 8-lane groups, 16-edge pipeline (R8 version).
__global__ __launch_bounds__(256) void agg64_add8(
    const unsigned char* __restrict__ xq, const int* __restrict__ row_ptr,
    const int* __restrict__ srcs, float* __restrict__ out) {
    int wave = (blockIdx.x * 256 + threadIdx.x) >> 6;
    int lane = threadIdx.x & 63;
    int sl = lane & 7;
    int n = wave * 8 + (lane >> 3);
    if (n >= NODES) return;
    int beg = row_ptr[n], end = row_ptr[n + 1];
    int gb = lane & 56;  // group base lane (g*8)

    f32x2 A0[4], A1[4];
#pragma unroll
    for (int i = 0; i < 4; ++i) { A0[i] = {0.f, 0.f}; A1[i] = {0.f, 0.f}; }

    const unsigned char* xs = xq + sl * 8;
    for (int base = beg; base < end; base += 16) {
        int i0 = base + sl, i1 = base + 8 + sl;
        int sv0 = (i0 < end) ? srcs[i0] : NODES;  // zero pad row
        int sv1 = (i1 < end) ? srcs[i1] : NODES;
        uint2 vv[16];
#pragma unroll
        for (int j = 0; j < 8; ++j) {
            int s = __shfl(sv0, gb + j, 64);
            vv[j] = *reinterpret_cast<const uint2*>(xs + (size_t)s * 64);
        }
#pragma unroll
        for (int j = 0; j < 8; ++j) {
            int s = __shfl(sv1, gb + j, 64);
            vv[8 + j] = *reinterpret_cast<const uint2*>(xs + (size_t)s * 64);
        }
#pragma unroll
        for (int j = 0; j < 16; ++j) addpk8((j & 1) ? A1 : A0, vv[j]);
    }

    float inv = 1.0f / fmaxf((float)(end - beg), 1.0f);
    f32x2 iv = {inv, inv};
    float* op = out + (size_t)n * 64 + sl * 8;
    f32x2 r0 = *reinterpret_cast<f32x2*>(op);
    f32x2 r1 = *reinterpret_cast<f32x2*>(op + 2);
    f32x2 r2 = *reinterpret_cast<f32x2*>(op + 4);
    f32x2 r3 = *reinterpret_cast<f32x2*>(op + 6);
    r0 = pkfma(pkadd(A0[0], A1[0]), iv, r0);
    r1 = pkfma(pkadd(A0[1], A1[1]), iv, r1);
    r2 = pkfma(pkadd(A0[2], A1[2]), iv, r2);
    r3 = pkfma(pkadd(A0[3], A1[3]), iv, r3);
    *reinterpret_cast<f32x2*>(op) = r0;
    *reinterpret_cast<f32x2*>(op + 2) = r1;
    *reinterpret_cast<f32x2*>(op + 4) = r2;
    *reinterpret_cast<f32x2*>(op + 6) = r3;
}

// ---------------- Fused MLP v6: 64-row chunks, wave-disjoint A ----

__global__ __launch_bounds__(256, 2) void fused_mlp(
    const unsigned short* __restrict__ featb, const unsigned short* __restrict__ agg,
    const unsigned short* __restrict__ Wt1s, const unsigned short* __restrict__ Wt1n,
    const float* __restrict__ b1, const unsigned short* __restrict__ Wt2s,
    const unsigned short* __restrict__ Wt2n, const float* __restrict__ b2,
    unsigned char* __restrict__ x1h8, float* __restrict__ outp) {
    __shared__ __align__(16) unsigned short w1t[32768];    // 64 KB, swizzled
    __shared__ __align__(16) unsigned short x1t[64 * 128]; // 16 KB, swizzled
    int wid = threadIdx.x >> 6, lane = threadIdx.x & 63;
    int l15 = lane & 15, quad = lane >> 4;

    // stage W1 -> LDS with 16B-slot swizzle
    {
        const uint4* gs = reinterpret_cast<const uint4*>(Wt1s);
        const uint4* gn = reinterpret_cast<const uint4*>(Wt1n);
        uint4* ls = reinterpret_cast<uint4*>(w1t);
        uint4* ln = ls + 2048;
#pragma unroll
        for (int i = 0; i < 8; ++i) {
            int g = threadIdx.x + i * 256;
            int sw = (g & ~15) | ((g & 15) ^ ((g >> 4) & 7));
            ls[sw] = gs[g];
            ln[sw] = gn[g];
        }
    }

    // B2 strips pinned in registers (8 frags, volatile asm)
    int col2 = wid * 16 + l15;
    bf16x8 B2s[4], B2n[4];
#pragma unroll
    for (int k = 0; k < 4; ++k) {
        B2s[k] = gl16(Wt2s + (size_t)col2 * 128 + k * 32 + quad * 8);
        B2n[k] = gl16(Wt2n + (size_t)col2 * 128 + k * 32 + quad * 8);
    }
    float bv2 = b2[col2];
    float bv1[8];
#pragma unroll
    for (int nt = 0; nt < 8; ++nt) bv1[nt] = b1[nt * 16 + l15];

    // per-wave disjoint 16-row A slice
    auto loadA = [&](int cc, bf16x8 (&Afd)[4], bf16x8 (&Aad)[4]) {
        int r = cc * 64 + wid * 16 + l15;
        if (r >= NODES) r = NODES - 1;  // tail clamp (stores guarded)
        const unsigned short* fp = featb + (size_t)r * 128 + quad * 8;
        const unsigned short* ap = agg + (size_t)r * 128 + quad * 8;
#pragma unroll
        for (int k = 0; k < 4; ++k) {
            Afd[k] = *reinterpret_cast<const bf16x8*>(fp + k * 32);
            Aad[k] = *reinterpret_cast<const bf16x8*>(ap + k * 32);
        }
    };

    bf16x8 Af[4], Aa[4];
    int c = blockIdx.x;
    if (c < NCH64) loadA(c, Af, Aa);

    // drain pinned B2 loads; fence; W1 visible (rule #18 ordering)
    asm volatile("s_waitcnt vmcnt(0)" ::: "memory");
    __builtin_amdgcn_sched_barrier(0);
    __syncthreads();

    int swz = l15 & 7;  // W1 read swizzle key (col&7 = l15&7)

    for (; c < NCH64; c += MLPGRID) {
        int rbase = c * 64;
        int cn = c + MLPGRID;

        // ---- phase 1: my 16 rows x all 128 W1 cols ----
        f32x4 acc[8];
#pragma unroll
        for (int nt = 0; nt < 8; ++nt) acc[nt] = {0.f, 0.f, 0.f, 0.f};
#pragma unroll
        for (int k = 0; k < 4; ++k) {
            int so = ((k * 4 + quad) ^ swz) << 3;  // swizzled 16B slot, in shorts
#pragma unroll
            for (int nt = 0; nt < 8; ++nt) {
                const unsigned short* wb = w1t + (size_t)(nt * 16 + l15) * 128;
                bf16x8 b1s = *reinterpret_cast<const bf16x8*>(wb + so);
                bf16x8 b1n = *reinterpret_cast<const bf16x8*>(wb + 16384 + so);
                acc[nt] = __builtin_amdgcn_mfma_f32_16x16x32_bf16(Af[k], b1s, acc[nt], 0, 0, 0);
                acc[nt] = __builtin_amdgcn_mfma_f32_16x16x32_bf16(Aa[k], b1n, acc[nt], 0, 0, 0);
            }
        }

        // prefetch next chunk's A (overlaps epilogue + phase 2)
        bf16x8 Pf[4], Pa[4];
        if (cn < NCH64) loadA(cn, Pf, Pa);

        // ---- epilogue: relu+bias -> x1t (XOR slot swizzle) ----
#pragma unroll
        for (int nt = 0; nt < 8; ++nt)
#pragma unroll
            for (int rr = 0; rr < 4; ++rr) {
                float v = fmaxf(acc[nt][rr] + bv1[nt], 0.f);
                int row = wid * 16 + quad * 4 + rr;        // 0..63
                int col = nt * 16 + l15;                   // 0..127
                int slot = (col >> 3) ^ (row & 7);         // XOR low 3 bits
                x1t[row * 128 + slot * 8 + (col & 7)] = f2b(v);
            }
        __syncthreads();

        // ---- phase 2: my 16 cols x all 64 rows ----
        f32x4 a2s[4], a2n[4];
#pragma unroll
        for (int mt = 0; mt < 4; ++mt) { a2s[mt] = {0.f, 0.f, 0.f, 0.f}; a2n[mt] = {0.f, 0.f, 0.f, 0.f}; }
#pragma unroll
        for (int k = 0; k < 4; ++k)
#pragma unroll
            for (int mt = 0; mt < 4; ++mt) {
                int row = mt * 16 + l15;
                int slot = (k * 4 + quad) ^ (row & 7);
                bf16x8 a = *reinterpret_cast<const bf16x8*>(x1t + row * 128 + slot * 8);
                a2s[mt] = __builtin_amdgcn_mfma_f32_16x16x32_bf16(a, B2s[k], a2s[mt], 0, 0, 0);
                a2n[mt] = __builtin_amdgcn_mfma_f32_16x16x32_bf16(a, B2n[k], a2n[mt], 0, 0, 0);
            }
        __syncthreads();  // x1t consumed; next iteration may overwrite

        // ---- stores ----
#pragma unroll
        for (int mt = 0; mt < 4; ++mt)
#pragma unroll
            for (int rr = 0; rr < 4; ++rr) {
                int row = rbase + mt * 16 + quad * 4 + rr;
                if (row < NODES) {
                    float vn = a2n[mt][rr];
                    int pk = __builtin_amdgcn_cvt_pk_fp8_f32(vn, vn, 0, false);
                    x1h8[(size_t)row * 64 + col2] = (unsigned char)(pk & 0xFF);
                    outp[(size_t)row * 64 + col2] = a2s[mt][rr] + bv2;
                }
            }

        if (cn < NCH64) {
#pragma unroll
            for (int k = 0; k < 4; ++k) {
                Af[k] = Pf[k];
                Aa[k] = Pa[k];
            }
        }
    }
}

// ---------------- launch ----------------

extern "C" void kernel_launch(void* const* d_in, const int* in_sizes, int n_in,
                              void* d_out, int out_size, void* d_ws, size_t ws_size,
                              hipStream_t stream) {
    const float* features = (const float*)d_in[0];
    const int* esrc = (const int*)d_in[1];
    const int* edst = (const int*)d_in[2];
    const float* W1s = (const float*)d_in[3];
    const float* W1n = (const float*)d_in[4];
    const float* b1  = (const float*)d_in[5];
    const float* W2s = (const float*)d_in[6];
    const float* W2n = (const float*)d_in[7];
    const float* b2  = (const float*)d_in[8];
    float* out = (float*)d_out;

    char* ws = (char*)d_ws;
    size_t off = 0;
    auto alloc = [&](size_t bytes) {
        void* p = ws + off;
        off += (bytes + 255) & ~(size_t)255;
        return p;
    };
    int* bucket_cnt = (int*)alloc(512 * 4);
    int* bucket_off = (int*)alloc(512 * 4);
    int* gcursor    = (int*)alloc(512 * 4);
    int* row_ptr    = (int*)alloc((size_t)(NODES + 1) * 4);
    int* src_sorted = (int*)alloc((size_t)EDGES * 4);
    unsigned* pairs = (unsigned*)alloc((size_t)EDGES * 4);
    unsigned short* featb = (unsigned short*)alloc((size_t)NODES * 128 * 2);
    unsigned char*  feat8 = (unsigned char*)alloc((size_t)(NODES + 1) * 128);  // +zero pad row
    unsigned short* agg1  = (unsigned short*)alloc((size_t)NODES * 128 * 2);
    unsigned char*  x1h8  = (unsigned char*)alloc((size_t)(NODES + 1) * 64);   // +zero pad row
    unsigned short* Wt1s  = (unsigned short*)alloc(16384 * 2);
    unsigned short* Wt1n  = (unsigned short*)alloc(16384 * 2);
    unsigned short* Wt2s  = (unsigned short*)alloc(8192 * 2);
    unsigned short* Wt2n  = (unsigned short*)alloc(8192 * 2);

    // zero pad rows + bucket counters
    hipMemsetAsync(bucket_cnt, 0, 512 * 4, stream);
    hipMemsetAsync(feat8 + (size_t)NODES * 128, 0, 128, stream);
    hipMemsetAsync(x1h8 + (size_t)NODES * 64, 0, 64, stream);

    // fused conversions + coarse histogram
    conv_hist<<<CONVB + (EDGES + 16383) / 16384, 256, 0, stream>>>(
        features, featb, feat8, NODES * 128 / 4, W1s, W1n, W2s, W2n,
        Wt1s, Wt1n, Wt2s, Wt2n, edst, bucket_cnt);

    bscan_kernel<<<1, 512, 0, stream>>>(bucket_cnt, bucket_off, gcursor, row_ptr);
    binscat_kernel<<<(EDGES + CHUNK - 1) / CHUNK, 256, 0, stream>>>(esrc, edst, gcursor, pairs);
    localsort_kernel<<<NBUCK, 256, 0, stream>>>(pairs, bucket_off, row_ptr, src_sorted);

    // layer 1 aggregation: XCD-sliced (slice = bid&7 -> XCD-resident L2)
    agg128_fp8<<<8 * NCH32, 256, 0, stream>>>(feat8, row_ptr, src_sorted, agg1);

    // fused MLP v6: 64-row chunks, wave-disjoint A, W1 in LDS
    fused_mlp<<<MLPGRID, 256, 0, stream>>>(featb, agg1, Wt1s, Wt1n, b1, Wt2s, Wt2n, b2, x1h8, out);

    // out += mean-neigh(x1h); 8 nodes/wave, 16-deep
    agg64_add8<<<(NODES / 8 * 64 + 255) / 256, 256, 0, stream>>>(x1h8, row_ptr, src_sorted, out);
}

// Round 12
// 279.585 us; speedup vs baseline: 1.3651x; 1.3651x over previous
//
#include <hip/hip_runtime.h>

#define NODES 100000
#define EDGES 1600000
#define BSH 8
#define NBUCK ((NODES + 255) >> BSH)   // 391
#define CHUNK 4096
#define LMAX 8192
#define NCH64 ((NODES + 63) / 64)      // 1563 (tail clamped)
#define NCH32 ((NODES + 31) / 32)      // 3125
#define CONVB 12500                    // blocks for conv part of conv_hist
#define MLPGRID 512                    // 2 blocks/CU (LDS = 80 KB exactly)
// IN_F = HID_F = 128, OUT_F = 64

using bf16x8 = __attribute__((ext_vector_type(8))) short;
using f32x4  = __attribute__((ext_vector_type(4))) float;
using f32x2  = __attribute__((ext_vector_type(2))) float;

__device__ __forceinline__ unsigned short f2b(float f) {
    unsigned u = __builtin_bit_cast(unsigned, f);
    unsigned r = (u + 0x7FFFu + ((u >> 16) & 1u)) >> 16;
    return (unsigned short)r;
}

// ---- packed f32 helpers (CDNA VOP3P; dual-pump FP32) ----
__device__ __forceinline__ f32x2 pkadd(f32x2 a, f32x2 b) {
    f32x2 d;
    asm("v_pk_add_f32 %0, %1, %2" : "=v"(d) : "v"(a), "v"(b));
    return d;
}
__device__ __forceinline__ f32x2 pkfma(f32x2 a, f32x2 b, f32x2 c) {
    f32x2 d;
    asm("v_pk_fma_f32 %0, %1, %2, %3" : "=v"(d) : "v"(a), "v"(b), "v"(c));
    return d;
}
__device__ __forceinline__ unsigned cvt2bf(float lo, float hi) {
    unsigned r;
    asm("v_cvt_pk_bf16_f32 %0, %1, %2" : "=v"(r) : "v"(lo), "v"(hi));
    return r;
}

// pinned 16B global load (volatile: cannot be sunk/rematerialized)
__device__ __forceinline__ bf16x8 gl16(const unsigned short* p) {
    bf16x8 r;
    asm volatile("global_load_dwordx4 %0, %1, off" : "=&v"(r) : "v"(p));
    return r;
}

// unpack 8 fp8 (uint2) and accumulate into 4 packed-f32 accumulators
__device__ __forceinline__ void addpk8(f32x2* a, uint2 v) {
    a[0] = pkadd(a[0], __builtin_amdgcn_cvt_pk_f32_fp8((int)v.x, false));
    a[1] = pkadd(a[1], __builtin_amdgcn_cvt_pk_f32_fp8((int)v.x, true));
    a[2] = pkadd(a[2], __builtin_amdgcn_cvt_pk_f32_fp8((int)v.y, false));
    a[3] = pkadd(a[3], __builtin_amdgcn_cvt_pk_f32_fp8((int)v.y, true));
}

// ---------------- fused conversions + coarse histogram ----------------
// fp8 features are written SLICE-MAJOR: feat8T[8][NODES][16] bytes, so a
// 16-feature column slice is a contiguous 1.6 MB block (fits an XCD L2).
// R11 lesson: a 16B column slice of a row-major table shares its 128B
// cache line with the whole row -> slicing without transposing 8x'd HBM.

__global__ __launch_bounds__(256) void conv_hist(
    const float* __restrict__ in, unsigned short* __restrict__ outb,
    unsigned char* __restrict__ outq, int n4,
    const float* __restrict__ W1s, const float* __restrict__ W1n,
    const float* __restrict__ W2s, const float* __restrict__ W2n,
    unsigned short* __restrict__ Wt1s, unsigned short* __restrict__ Wt1n,
    unsigned short* __restrict__ Wt2s, unsigned short* __restrict__ Wt2n,
    const int* __restrict__ dst, int* __restrict__ bucket_cnt) {
    int t = threadIdx.x;
    if (blockIdx.x < CONVB) {
        int i = blockIdx.x * 256 + t;
        if (i < n4) {
            float4 v = reinterpret_cast<const float4*>(in)[i];
            uint2 o;
            o.x = (unsigned)f2b(v.x) | ((unsigned)f2b(v.y) << 16);
            o.y = (unsigned)f2b(v.z) | ((unsigned)f2b(v.w) << 16);
            reinterpret_cast<uint2*>(outb)[i] = o;
            int pk = __builtin_amdgcn_cvt_pk_fp8_f32(v.x, v.y, 0, false);
            pk = __builtin_amdgcn_cvt_pk_fp8_f32(v.z, v.w, pk, true);
            int nd = i >> 5;          // node
            int m = i & 31;           // float4 index within row
            int s = m >> 2;           // slice 0..7
            int b = (m & 3) * 4;      // byte offset within 16B slice row
            *reinterpret_cast<unsigned*>(outq + ((size_t)s * NODES + nd) * 16 + b) = (unsigned)pk;
        }
        if (i < 16384) {
            int k = i >> 7, n = i & 127;
            Wt1s[n * 128 + k] = f2b(W1s[i]);
            Wt1n[n * 128 + k] = f2b(W1n[i]);
        }
        if (i < 8192) {
            int k = i >> 6, n = i & 63;
            Wt2s[n * 128 + k] = f2b(W2s[i]);
            Wt2n[n * 128 + k] = f2b(W2n[i]);
        }
        return;
    }
    // ---- bhist part ----
    __shared__ int lcnt[512];
    lcnt[t] = 0; lcnt[t + 256] = 0;
    __syncthreads();
    int base = (blockIdx.x - CONVB) * 16384;
    int n = EDGES - base;
    if (n > 16384) n = 16384;
    const int4* d4 = reinterpret_cast<const int4*>(dst + base);
    for (int i = t; i < (n >> 2); i += 256) {
        int4 d = d4[i];
        atomicAdd(&lcnt[d.x >> BSH], 1);
        atomicAdd(&lcnt[d.y >> BSH], 1);
        atomicAdd(&lcnt[d.z >> BSH], 1);
        atomicAdd(&lcnt[d.w >> BSH], 1);
    }
    for (int i = (n & ~3) + t; i < n; i += 256) atomicAdd(&lcnt[dst[base + i] >> BSH], 1);
    __syncthreads();
    if (lcnt[t]) atomicAdd(&bucket_cnt[t], lcnt[t]);
    if (lcnt[t + 256]) atomicAdd(&bucket_cnt[t + 256], lcnt[t + 256]);
}

__global__ void bscan_kernel(const int* __restrict__ bucket_cnt, int* __restrict__ bucket_off,
                             int* __restrict__ gcursor, int* __restrict__ row_ptr) {
    __shared__ int sh[512];
    int t = threadIdx.x;
    int v = (t < NBUCK) ? bucket_cnt[t] : 0;
    sh[t] = v;
    __syncthreads();
    for (int off = 1; off < 512; off <<= 1) {
        int x = (t >= off) ? sh[t - off] : 0;
        __syncthreads();
        sh[t] += x;
        __syncthreads();
    }
    int excl = sh[t] - v;
    if (t < NBUCK) { bucket_off[t] = excl; gcursor[t] = excl; }
    if (t == NBUCK) bucket_off[t] = EDGES;
    if (t == 0) row_ptr[NODES] = EDGES;
}

// Bin edges by coarse bucket; write packed (dst&255)<<24|src runs.
__global__ __launch_bounds__(256) void binscat_kernel(
    const int* __restrict__ src, const int* __restrict__ dst,
    int* __restrict__ gcursor, unsigned* __restrict__ pairs) {
    __shared__ int cnt[512];
    __shared__ int scn[512];
    __shared__ int gbs[512];
    __shared__ int cur[512];
    __shared__ uint2 stage[CHUNK];
    int t = threadIdx.x;
    int base = blockIdx.x * CHUNK;
    int n = EDGES - base;
    if (n > CHUNK) n = CHUNK;

    cnt[t] = 0; cnt[t + 256] = 0;
    __syncthreads();

    uint2 my[16];
#pragma unroll
    for (int i = 0; i < 16; ++i) {
        int idx = t + i * 256;
        if (idx < n) {
            int d = dst[base + idx];
            int s = src[base + idx];
            my[i] = make_uint2((unsigned)d, (unsigned)s);
            atomicAdd(&cnt[d >> BSH], 1);
        } else {
            my[i] = make_uint2(0xFFFFFFFFu, 0);
        }
    }
    __syncthreads();
    scn[t] = cnt[t]; scn[t + 256] = cnt[t + 256];
    __syncthreads();
    for (int off = 1; off < 512; off <<= 1) {
        int a0 = (t >= off) ? scn[t - off] : 0;
        int a1 = (t + 256 >= off) ? scn[t + 256 - off] : 0;
        __syncthreads();
        scn[t] += a0; scn[t + 256] += a1;
        __syncthreads();
    }
    cur[t] = scn[t] - cnt[t];
    cur[t + 256] = scn[t + 256] - cnt[t + 256];
    __syncthreads();
#pragma unroll
    for (int i = 0; i < 16; ++i) {
        if (my[i].x != 0xFFFFFFFFu) {
            int b = (int)(my[i].x >> BSH);
            int p = atomicAdd(&cur[b], 1);
            stage[p] = my[i];
        }
    }
    for (int b2 = t; b2 < 512; b2 += 256) {
        int c = cnt[b2];
        gbs[b2] = (c > 0 && b2 < NBUCK) ? atomicAdd(&gcursor[b2], c) : 0;
    }
    __syncthreads();
    for (int idx = t; idx < n; idx += 256) {
        uint2 p = stage[idx];
        int b = (int)(p.x >> BSH);
        int excl = scn[b] - cnt[b];
        pairs[gbs[b] + idx - excl] = ((p.x & 255u) << 24) | p.y;
    }
}

__global__ __launch_bounds__(256) void localsort_kernel(
    const unsigned* __restrict__ pairs, const int* __restrict__ bucket_off,
    int* __restrict__ row_ptr, int* __restrict__ src_sorted) {
    __shared__ int cnt[256];
    __shared__ int cur[256];
    __shared__ int stage[LMAX];
    int b = blockIdx.x;
    int t = threadIdx.x;
    int node0 = b << BSH;
    int pbeg = bucket_off[b], pend = bucket_off[b + 1];
    int n = pend - pbeg;
    cnt[t] = 0;
    __syncthreads();
    for (int e = pbeg + t; e < pend; e += 256)
        atomicAdd(&cnt[(int)(pairs[e] >> 24)], 1);
    __syncthreads();
    int v = cnt[t];
    cur[t] = v;
    __syncthreads();
    for (int off = 1; off < 256; off <<= 1) {
        int x = (t >= off) ? cur[t - off] : 0;
        __syncthreads();
        cur[t] += x;
        __syncthreads();
    }
    int excl = cur[t] - v;
    int node = node0 + t;
    if (node < NODES) row_ptr[node] = pbeg + excl;
    cur[t] = excl;
    __syncthreads();
    if (n <= LMAX) {
        for (int e = pbeg + t; e < pend; e += 256) {
            unsigned p = pairs[e];
            int pos = atomicAdd(&cur[(int)(p >> 24)], 1);
            stage[pos] = (int)(p & 0xFFFFFFu);
        }
        __syncthreads();
        for (int i = t; i < n; i += 256) src_sorted[pbeg + i] = stage[i];
    } else {
        for (int e = pbeg + t; e < pend; e += 256) {
            unsigned p = pairs[e];
            int pos = atomicAdd(&cur[(int)(p >> 24)], 1);
            src_sorted[pbeg + pos] = (int)(p & 0xFFFFFFu);
        }
    }
}

// ---------------- Mean aggregation, fp8 gather ----------------
// v6: XCD-sliced over a SLICE-MAJOR table. slice = blockIdx&7 -> XCD
// (round-robin dispatch); slice s is a contiguous 1.6 MB block -> truly
// L2-resident per XCD. Lane-per-edge (each edge counted once), unroll-2:
// 16 gathers/group in flight. 3-hop shfl_xor reduce; lanes 0,1 write 16B.

__global__ __launch_bounds__(256) void agg128_fp8(
    const unsigned char* __restrict__ xq,   // [8][NODES][16] slice-major
    const int* __restrict__ row_ptr,
    const int* __restrict__ srcs, unsigned short* __restrict__ out) {
    int bid = blockIdx.x;
    int s = bid & 7;                  // feature slice == XCD
    int chunk = bid >> 3;             // 32 nodes per block
    int lane = threadIdx.x & 63;
    int sl = lane & 7;
    int n = chunk * 32 + ((int)(threadIdx.x >> 6)) * 8 + (lane >> 3);
    if (n >= NODES) return;
    int beg = row_ptr[n], end = row_ptr[n + 1];

    f32x2 A0[4], A1[4], B0[4], B1[4];
#pragma unroll
    for (int i = 0; i < 4; ++i) {
        A0[i] = {0.f, 0.f}; A1[i] = {0.f, 0.f};
        B0[i] = {0.f, 0.f}; B1[i] = {0.f, 0.f};
    }

    const unsigned char* xs = xq + (size_t)s * NODES * 16;
    int e = beg + sl;
    for (; e + 8 < end; e += 16) {
        int s0 = srcs[e];
        int s1 = srcs[e + 8];
        uint4 v0 = *reinterpret_cast<const uint4*>(xs + (size_t)s0 * 16);
        uint4 v1 = *reinterpret_cast<const uint4*>(xs + (size_t)s1 * 16);
        addpk8(A0, make_uint2(v0.x, v0.y));
        addpk8(A1, make_uint2(v0.z, v0.w));
        addpk8(B0, make_uint2(v1.x, v1.y));
        addpk8(B1, make_uint2(v1.z, v1.w));
    }
    if (e < end) {
        int s0 = srcs[e];
        uint4 v0 = *reinterpret_cast<const uint4*>(xs + (size_t)s0 * 16);
        addpk8(A0, make_uint2(v0.x, v0.y));
        addpk8(A1, make_uint2(v0.z, v0.w));
    }

#pragma unroll
    for (int i = 0; i < 4; ++i) {
        A0[i] = pkadd(A0[i], B0[i]);
        A1[i] = pkadd(A1[i], B1[i]);
    }
    // reduce across the 8 lanes of the group (xor 1,2,4)
#pragma unroll
    for (int i = 0; i < 4; ++i) {
        f32x2 t;
#pragma unroll
        for (int h = 1; h <= 4; h <<= 1) {
            t[0] = __shfl_xor(A0[i][0], h, 64);
            t[1] = __shfl_xor(A0[i][1], h, 64);
            A0[i] = pkadd(A0[i], t);
            t[0] = __shfl_xor(A1[i][0], h, 64);
            t[1] = __shfl_xor(A1[i][1], h, 64);
            A1[i] = pkadd(A1[i], t);
        }
    }

    float inv = 1.0f / fmaxf((float)(end - beg), 1.0f);
    unsigned short* op = out + (size_t)n * 128 + s * 16;
    if (sl == 0) {
        uint4 o0;
        o0.x = cvt2bf(A0[0][0] * inv, A0[0][1] * inv);
        o0.y = cvt2bf(A0[1][0] * inv, A0[1][1] * inv);
        o0.z = cvt2bf(A0[2][0] * inv, A0[2][1] * inv);
        o0.w = cvt2bf(A0[3][0] * inv, A0[3][1] * inv);
        *reinterpret_cast<uint4*>(op) = o0;
    } else if (sl == 1) {
        uint4 o1;
        o1.x = cvt2bf(A1[0][0] * inv, A1[0][1] * inv);
        o1.y = cvt2bf(A1[1][0] * inv, A1[1][1] * inv);
        o1.z = cvt2bf(A1[2][0] * inv, A1[2][1] * inv);
        o1.w = cvt2bf(A1[3][0] * inv, A1[3][1] * inv);
        *reinterpret_cast<uint4*>(op + 8) = o1;
    }
}

// agg64: group-per-node, 8-lane groups, 16-edge pipeline (R8 version).
__global__ __launch_bounds__(256) void agg64_add8(
    const unsigned char* __restrict__ xq, const int* __restrict__ row_ptr,
    const int* __restrict__ srcs, float* __restrict__ out) {
    int wave = (blockIdx.x * 256 + threadIdx.x) >> 6;
    int lane = threadIdx.x & 63;
    int sl = lane & 7;
    int n = wave * 8 + (lane >> 3);
    if (n >= NODES) return;
    int beg = row_ptr[n], end = row_ptr[n + 1];
    int gb = lane & 56;  // group base lane (g*8)

    f32x2 A0[4], A1[4];
#pragma unroll
    for (int i = 0; i < 4; ++i) { A0[i] = {0.f, 0.f}; A1[i] = {0.f, 0.f}; }

    const unsigned char* xs = xq + sl * 8;
    for (int base = beg; base < end; base += 16) {
        int i0 = base + sl, i1 = base + 8 + sl;
        int sv0 = (i0 < end) ? srcs[i0] : NODES;  // zero pad row
        int sv1 = (i1 < end) ? srcs[i1] : NODES;
        uint2 vv[16];
#pragma unroll
        for (int j = 0; j < 8; ++j) {
            int s = __shfl(sv0, gb + j, 64);
            vv[j] = *reinterpret_cast<const uint2*>(xs + (size_t)s * 64);
        }
#pragma unroll
        for (int j = 0; j < 8; ++j) {
            int s = __shfl(sv1, gb + j, 64);
            vv[8 + j] = *reinterpret_cast<const uint2*>(xs + (size_t)s * 64);
        }
#pragma unroll
        for (int j = 0; j < 16; ++j) addpk8((j & 1) ? A1 : A0, vv[j]);
    }

    float inv = 1.0f / fmaxf((float)(end - beg), 1.0f);
    f32x2 iv = {inv, inv};
    float* op = out + (size_t)n * 64 + sl * 8;
    f32x2 r0 = *reinterpret_cast<f32x2*>(op);
    f32x2 r1 = *reinterpret_cast<f32x2*>(op + 2);
    f32x2 r2 = *reinterpret_cast<f32x2*>(op + 4);
    f32x2 r3 = *reinterpret_cast<f32x2*>(op + 6);
    r0 = pkfma(pkadd(A0[0], A1[0]), iv, r0);
    r1 = pkfma(pkadd(A0[1], A1[1]), iv, r1);
    r2 = pkfma(pkadd(A0[2], A1[2]), iv, r2);
    r3 = pkfma(pkadd(A0[3], A1[3]), iv, r3);
    *reinterpret_cast<f32x2*>(op) = r0;
    *reinterpret_cast<f32x2*>(op + 2) = r1;
    *reinterpret_cast<f32x2*>(op + 4) = r2;
    *reinterpret_cast<f32x2*>(op + 6) = r3;
}

// ---------------- Fused MLP v6: 64-row chunks, wave-disjoint A ----

__global__ __launch_bounds__(256, 2) void fused_mlp(
    const unsigned short* __restrict__ featb, const unsigned short* __restrict__ agg,
    const unsigned short* __restrict__ Wt1s, const unsigned short* __restrict__ Wt1n,
    const float* __restrict__ b1, const unsigned short* __restrict__ Wt2s,
    const unsigned short* __restrict__ Wt2n, const float* __restrict__ b2,
    unsigned char* __restrict__ x1h8, float* __restrict__ outp) {
    __shared__ __align__(16) unsigned short w1t[32768];    // 64 KB, swizzled
    __shared__ __align__(16) unsigned short x1t[64 * 128]; // 16 KB, swizzled
    int wid = threadIdx.x >> 6, lane = threadIdx.x & 63;
    int l15 = lane & 15, quad = lane >> 4;

    // stage W1 -> LDS with 16B-slot swizzle
    {
        const uint4* gs = reinterpret_cast<const uint4*>(Wt1s);
        const uint4* gn = reinterpret_cast<const uint4*>(Wt1n);
        uint4* ls = reinterpret_cast<uint4*>(w1t);
        uint4* ln = ls + 2048;
#pragma unroll
        for (int i = 0; i < 8; ++i) {
            int g = threadIdx.x + i * 256;
            int sw = (g & ~15) | ((g & 15) ^ ((g >> 4) & 7));
            ls[sw] = gs[g];
            ln[sw] = gn[g];
        }
    }

    // B2 strips pinned in registers (8 frags, volatile asm)
    int col2 = wid * 16 + l15;
    bf16x8 B2s[4], B2n[4];
#pragma unroll
    for (int k = 0; k < 4; ++k) {
        B2s[k] = gl16(Wt2s + (size_t)col2 * 128 + k * 32 + quad * 8);
        B2n[k] = gl16(Wt2n + (size_t)col2 * 128 + k * 32 + quad * 8);
    }
    float bv2 = b2[col2];
    float bv1[8];
#pragma unroll
    for (int nt = 0; nt < 8; ++nt) bv1[nt] = b1[nt * 16 + l15];

    // per-wave disjoint 16-row A slice
    auto loadA = [&](int cc, bf16x8 (&Afd)[4], bf16x8 (&Aad)[4]) {
        int r = cc * 64 + wid * 16 + l15;
        if (r >= NODES) r = NODES - 1;  // tail clamp (stores guarded)
        const unsigned short* fp = featb + (size_t)r * 128 + quad * 8;
        const unsigned short* ap = agg + (size_t)r * 128 + quad * 8;
#pragma unroll
        for (int k = 0; k < 4; ++k) {
            Afd[k] = *reinterpret_cast<const bf16x8*>(fp + k * 32);
            Aad[k] = *reinterpret_cast<const bf16x8*>(ap + k * 32);
        }
    };

    bf16x8 Af[4], Aa[4];
    int c = blockIdx.x;
    if (c < NCH64) loadA(c, Af, Aa);

    // drain pinned B2 loads; fence; W1 visible (rule #18 ordering)
    asm volatile("s_waitcnt vmcnt(0)" ::: "memory");
    __builtin_amdgcn_sched_barrier(0);
    __syncthreads();

    int swz = l15 & 7;  // W1 read swizzle key (col&7 = l15&7)

    for (; c < NCH64; c += MLPGRID) {
        int rbase = c * 64;
        int cn = c + MLPGRID;

        // ---- phase 1: my 16 rows x all 128 W1 cols ----
        f32x4 acc[8];
#pragma unroll
        for (int nt = 0; nt < 8; ++nt) acc[nt] = {0.f, 0.f, 0.f, 0.f};
#pragma unroll
        for (int k = 0; k < 4; ++k) {
            int so = ((k * 4 + quad) ^ swz) << 3;  // swizzled 16B slot, in shorts
#pragma unroll
            for (int nt = 0; nt < 8; ++nt) {
                const unsigned short* wb = w1t + (size_t)(nt * 16 + l15) * 128;
                bf16x8 b1s = *reinterpret_cast<const bf16x8*>(wb + so);
                bf16x8 b1n = *reinterpret_cast<const bf16x8*>(wb + 16384 + so);
                acc[nt] = __builtin_amdgcn_mfma_f32_16x16x32_bf16(Af[k], b1s, acc[nt], 0, 0, 0);
                acc[nt] = __builtin_amdgcn_mfma_f32_16x16x32_bf16(Aa[k], b1n, acc[nt], 0, 0, 0);
            }
        }

        // prefetch next chunk's A (overlaps epilogue + phase 2)
        bf16x8 Pf[4], Pa[4];
        if (cn < NCH64) loadA(cn, Pf, Pa);

        // ---- epilogue: relu+bias -> x1t (XOR slot swizzle) ----
#pragma unroll
        for (int nt = 0; nt < 8; ++nt)
#pragma unroll
            for (int rr = 0; rr < 4; ++rr) {
                float v = fmaxf(acc[nt][rr] + bv1[nt], 0.f);
                int row = wid * 16 + quad * 4 + rr;        // 0..63
                int col = nt * 16 + l15;                   // 0..127
                int slot = (col >> 3) ^ (row & 7);         // XOR low 3 bits
                x1t[row * 128 + slot * 8 + (col & 7)] = f2b(v);
            }
        __syncthreads();

        // ---- phase 2: my 16 cols x all 64 rows ----
        f32x4 a2s[4], a2n[4];
#pragma unroll
        for (int mt = 0; mt < 4; ++mt) { a2s[mt] = {0.f, 0.f, 0.f, 0.f}; a2n[mt] = {0.f, 0.f, 0.f, 0.f}; }
#pragma unroll
        for (int k = 0; k < 4; ++k)
#pragma unroll
            for (int mt = 0; mt < 4; ++mt) {
                int row = mt * 16 + l15;
                int slot = (k * 4 + quad) ^ (row & 7);
                bf16x8 a = *reinterpret_cast<const bf16x8*>(x1t + row * 128 + slot * 8);
                a2s[mt] = __builtin_amdgcn_mfma_f32_16x16x32_bf16(a, B2s[k], a2s[mt], 0, 0, 0);
                a2n[mt] = __builtin_amdgcn_mfma_f32_16x16x32_bf16(a, B2n[k], a2n[mt], 0, 0, 0);
            }
        __syncthreads();  // x1t consumed; next iteration may overwrite

        // ---- stores ----
#pragma unroll
        for (int mt = 0; mt < 4; ++mt)
#pragma unroll
            for (int rr = 0; rr < 4; ++rr) {
                int row = rbase + mt * 16 + quad * 4 + rr;
                if (row < NODES) {
                    float vn = a2n[mt][rr];
                    int pk = __builtin_amdgcn_cvt_pk_fp8_f32(vn, vn, 0, false);
                    x1h8[(size_t)row * 64 + col2] = (unsigned char)(pk & 0xFF);
                    outp[(size_t)row * 64 + col2] = a2s[mt][rr] + bv2;
                }
            }

        if (cn < NCH64) {
#pragma unroll
            for (int k = 0; k < 4; ++k) {
                Af[k] = Pf[k];
                Aa[k] = Pa[k];
            }
        }
    }
}

// ---------------- launch ----------------

extern "C" void kernel_launch(void* const* d_in, const int* in_sizes, int n_in,
                              void* d_out, int out_size, void* d_ws, size_t ws_size,
                              hipStream_t stream) {
    const float* features = (const float*)d_in[0];
    const int* esrc = (const int*)d_in[1];
    const int* edst = (const int*)d_in[2];
    const float* W1s = (const float*)d_in[3];
    const float* W1n = (const float*)d_in[4];
    const float* b1  = (const float*)d_in[5];
    const float* W2s = (const float*)d_in[6];
    const float* W2n = (const float*)d_in[7];
    const float* b2  = (const float*)d_in[8];
    float* out = (float*)d_out;

    char* ws = (char*)d_ws;
    size_t off = 0;
    auto alloc = [&](size_t bytes) {
        void* p = ws + off;
        off += (bytes + 255) & ~(size_t)255;
        return p;
    };
    int* bucket_cnt = (int*)alloc(512 * 4);
    int* bucket_off = (int*)alloc(512 * 4);
    int* gcursor    = (int*)alloc(512 * 4);
    int* row_ptr    = (int*)alloc((size_t)(NODES + 1) * 4);
    int* src_sorted = (int*)alloc((size_t)EDGES * 4);
    unsigned* pairs = (unsigned*)alloc((size_t)EDGES * 4);
    unsigned short* featb = (unsigned short*)alloc((size_t)NODES * 128 * 2);
    unsigned char*  feat8T = (unsigned char*)alloc((size_t)8 * NODES * 16);    // slice-major
    unsigned short* agg1  = (unsigned short*)alloc((size_t)NODES * 128 * 2);
    unsigned char*  x1h8  = (unsigned char*)alloc((size_t)(NODES + 1) * 64);   // +zero pad row
    unsigned short* Wt1s  = (unsigned short*)alloc(16384 * 2);
    unsigned short* Wt1n  = (unsigned short*)alloc(16384 * 2);
    unsigned short* Wt2s  = (unsigned short*)alloc(8192 * 2);
    unsigned short* Wt2n  = (unsigned short*)alloc(8192 * 2);

    // zero pad row (x1h8) + bucket counters
    hipMemsetAsync(bucket_cnt, 0, 512 * 4, stream);
    hipMemsetAsync(x1h8 + (size_t)NODES * 64, 0, 64, stream);

    // fused conversions + coarse histogram
    conv_hist<<<CONVB + (EDGES + 16383) / 16384, 256, 0, stream>>>(
        features, featb, feat8T, NODES * 128 / 4, W1s, W1n, W2s, W2n,
        Wt1s, Wt1n, Wt2s, Wt2n, edst, bucket_cnt);

    bscan_kernel<<<1, 512, 0, stream>>>(bucket_cnt, bucket_off, gcursor, row_ptr);
    binscat_kernel<<<(EDGES + CHUNK - 1) / CHUNK, 256, 0, stream>>>(esrc, edst, gcursor, pairs);
    localsort_kernel<<<NBUCK, 256, 0, stream>>>(pairs, bucket_off, row_ptr, src_sorted);

    // layer 1 aggregation: XCD-sliced over slice-major table
    agg128_fp8<<<8 * NCH32, 256, 0, stream>>>(feat8T, row_ptr, src_sorted, agg1);

    // fused MLP v6: 64-row chunks, wave-disjoint A, W1 in LDS
    fused_mlp<<<MLPGRID, 256, 0, stream>>>(featb, agg1, Wt1s, Wt1n, b1, Wt2s, Wt2n, b2, x1h8, out);

    // out += mean-neigh(x1h); 8 nodes/wave, 16-deep
    agg64_add8<<<(NODES / 8 * 64 + 255) / 256, 256, 0, stream>>>(x1h8, row_ptr, src_sorted, out);
}

// Round 13
// 238.884 us; speedup vs baseline: 1.5977x; 1.1704x over previous
//
#include <hip/hip_runtime.h>

#define NODES 100000
#define EDGES 1600000
#define BSH 8
#define NBUCK ((NODES + 255) >> BSH)   // 391
#define CHUNK 4096
#define LMAX 8192
#define NCH64 ((NODES + 63) / 64)      // 1563 (tail clamped)
#define CONVB 12500                    // blocks for conv part of conv_hist
#define MLPGRID 512                    // 2 blocks/CU (LDS = 80 KB exactly)
// IN_F = HID_F = 128, OUT_F = 64

using bf16x8 = __attribute__((ext_vector_type(8))) short;
using f32x4  = __attribute__((ext_vector_type(4))) float;
using f32x2  = __attribute__((ext_vector_type(2))) float;

__device__ __forceinline__ unsigned short f2b(float f) {
    unsigned u = __builtin_bit_cast(unsigned, f);
    unsigned r = (u + 0x7FFFu + ((u >> 16) & 1u)) >> 16;
    return (unsigned short)r;
}

// ---- packed f32 helpers (CDNA VOP3P; dual-pump FP32) ----
__device__ __forceinline__ f32x2 pkadd(f32x2 a, f32x2 b) {
    f32x2 d;
    asm("v_pk_add_f32 %0, %1, %2" : "=v"(d) : "v"(a), "v"(b));
    return d;
}
__device__ __forceinline__ f32x2 pkfma(f32x2 a, f32x2 b, f32x2 c) {
    f32x2 d;
    asm("v_pk_fma_f32 %0, %1, %2, %3" : "=v"(d) : "v"(a), "v"(b), "v"(c));
    return d;
}
__device__ __forceinline__ unsigned cvt2bf(float lo, float hi) {
    unsigned r;
    asm("v_cvt_pk_bf16_f32 %0, %1, %2" : "=v"(r) : "v"(lo), "v"(hi));
    return r;
}

// pinned 16B global load (volatile: cannot be sunk/rematerialized)
__device__ __forceinline__ bf16x8 gl16(const unsigned short* p) {
    bf16x8 r;
    asm volatile("global_load_dwordx4 %0, %1, off" : "=&v"(r) : "v"(p));
    return r;
}

// unpack 8 fp8 (uint2) and accumulate into 4 packed-f32 accumulators
__device__ __forceinline__ void addpk8(f32x2* a, uint2 v) {
    a[0] = pkadd(a[0], __builtin_amdgcn_cvt_pk_f32_fp8((int)v.x, false));
    a[1] = pkadd(a[1], __builtin_amdgcn_cvt_pk_f32_fp8((int)v.x, true));
    a[2] = pkadd(a[2], __builtin_amdgcn_cvt_pk_f32_fp8((int)v.y, false));
    a[3] = pkadd(a[3], __builtin_amdgcn_cvt_pk_f32_fp8((int)v.y, true));
}

// ---------------- fused conversions + coarse histogram ----------------

__global__ __launch_bounds__(256) void conv_hist(
    const float* __restrict__ in, unsigned short* __restrict__ outb,
    unsigned char* __restrict__ outq, int n4,
    const float* __restrict__ W1s, const float* __restrict__ W1n,
    const float* __restrict__ W2s, const float* __restrict__ W2n,
    unsigned short* __restrict__ Wt1s, unsigned short* __restrict__ Wt1n,
    unsigned short* __restrict__ Wt2s, unsigned short* __restrict__ Wt2n,
    const int* __restrict__ dst, int* __restrict__ bucket_cnt) {
    int t = threadIdx.x;
    if (blockIdx.x < CONVB) {
        int i = blockIdx.x * 256 + t;
        if (i < n4) {
            float4 v = reinterpret_cast<const float4*>(in)[i];
            uint2 o;
            o.x = (unsigned)f2b(v.x) | ((unsigned)f2b(v.y) << 16);
            o.y = (unsigned)f2b(v.z) | ((unsigned)f2b(v.w) << 16);
            reinterpret_cast<uint2*>(outb)[i] = o;
            int pk = __builtin_amdgcn_cvt_pk_fp8_f32(v.x, v.y, 0, false);
            pk = __builtin_amdgcn_cvt_pk_fp8_f32(v.z, v.w, pk, true);
            reinterpret_cast<unsigned*>(outq)[i] = (unsigned)pk;
        }
        if (i < 16384) {
            int k = i >> 7, n = i & 127;
            Wt1s[n * 128 + k] = f2b(W1s[i]);
            Wt1n[n * 128 + k] = f2b(W1n[i]);
        }
        if (i < 8192) {
            int k = i >> 6, n = i & 63;
            Wt2s[n * 128 + k] = f2b(W2s[i]);
            Wt2n[n * 128 + k] = f2b(W2n[i]);
        }
        return;
    }
    // ---- bhist part ----
    __shared__ int lcnt[512];
    lcnt[t] = 0; lcnt[t + 256] = 0;
    __syncthreads();
    int base = (blockIdx.x - CONVB) * 16384;
    int n = EDGES - base;
    if (n > 16384) n = 16384;
    const int4* d4 = reinterpret_cast<const int4*>(dst + base);
    for (int i = t; i < (n >> 2); i += 256) {
        int4 d = d4[i];
        atomicAdd(&lcnt[d.x >> BSH], 1);
        atomicAdd(&lcnt[d.y >> BSH], 1);
        atomicAdd(&lcnt[d.z >> BSH], 1);
        atomicAdd(&lcnt[d.w >> BSH], 1);
    }
    for (int i = (n & ~3) + t; i < n; i += 256) atomicAdd(&lcnt[dst[base + i] >> BSH], 1);
    __syncthreads();
    if (lcnt[t]) atomicAdd(&bucket_cnt[t], lcnt[t]);
    if (lcnt[t + 256]) atomicAdd(&bucket_cnt[t + 256], lcnt[t + 256]);
}

__global__ void bscan_kernel(const int* __restrict__ bucket_cnt, int* __restrict__ bucket_off,
                             int* __restrict__ gcursor, int* __restrict__ row_ptr) {
    __shared__ int sh[512];
    int t = threadIdx.x;
    int v = (t < NBUCK) ? bucket_cnt[t] : 0;
    sh[t] = v;
    __syncthreads();
    for (int off = 1; off < 512; off <<= 1) {
        int x = (t >= off) ? sh[t - off] : 0;
        __syncthreads();
        sh[t] += x;
        __syncthreads();
    }
    int excl = sh[t] - v;
    if (t < NBUCK) { bucket_off[t] = excl; gcursor[t] = excl; }
    if (t == NBUCK) bucket_off[t] = EDGES;
    if (t == 0) row_ptr[NODES] = EDGES;
}

// Bin edges by coarse bucket; write packed (dst&255)<<24|src runs.
__global__ __launch_bounds__(256) void binscat_kernel(
    const int* __restrict__ src, const int* __restrict__ dst,
    int* __restrict__ gcursor, unsigned* __restrict__ pairs) {
    __shared__ int cnt[512];
    __shared__ int scn[512];
    __shared__ int gbs[512];
    __shared__ int cur[512];
    __shared__ uint2 stage[CHUNK];
    int t = threadIdx.x;
    int base = blockIdx.x * CHUNK;
    int n = EDGES - base;
    if (n > CHUNK) n = CHUNK;

    cnt[t] = 0; cnt[t + 256] = 0;
    __syncthreads();

    uint2 my[16];
#pragma unroll
    for (int i = 0; i < 16; ++i) {
        int idx = t + i * 256;
        if (idx < n) {
            int d = dst[base + idx];
            int s = src[base + idx];
            my[i] = make_uint2((unsigned)d, (unsigned)s);
            atomicAdd(&cnt[d >> BSH], 1);
        } else {
            my[i] = make_uint2(0xFFFFFFFFu, 0);
        }
    }
    __syncthreads();
    scn[t] = cnt[t]; scn[t + 256] = cnt[t + 256];
    __syncthreads();
    for (int off = 1; off < 512; off <<= 1) {
        int a0 = (t >= off) ? scn[t - off] : 0;
        int a1 = (t + 256 >= off) ? scn[t + 256 - off] : 0;
        __syncthreads();
        scn[t] += a0; scn[t + 256] += a1;
        __syncthreads();
    }
    cur[t] = scn[t] - cnt[t];
    cur[t + 256] = scn[t + 256] - cnt[t + 256];
    __syncthreads();
#pragma unroll
    for (int i = 0; i < 16; ++i) {
        if (my[i].x != 0xFFFFFFFFu) {
            int b = (int)(my[i].x >> BSH);
            int p = atomicAdd(&cur[b], 1);
            stage[p] = my[i];
        }
    }
    for (int b2 = t; b2 < 512; b2 += 256) {
        int c = cnt[b2];
        gbs[b2] = (c > 0 && b2 < NBUCK) ? atomicAdd(&gcursor[b2], c) : 0;
    }
    __syncthreads();
    for (int idx = t; idx < n; idx += 256) {
        uint2 p = stage[idx];
        int b = (int)(p.x >> BSH);
        int excl = scn[b] - cnt[b];
        pairs[gbs[b] + idx - excl] = ((p.x & 255u) << 24) | p.y;
    }
}

__global__ __launch_bounds__(256) void localsort_kernel(
    const unsigned* __restrict__ pairs, const int* __restrict__ bucket_off,
    int* __restrict__ row_ptr, int* __restrict__ src_sorted) {
    __shared__ int cnt[256];
    __shared__ int cur[256];
    __shared__ int stage[LMAX];
    int b = blockIdx.x;
    int t = threadIdx.x;
    int node0 = b << BSH;
    int pbeg = bucket_off[b], pend = bucket_off[b + 1];
    int n = pend - pbeg;
    cnt[t] = 0;
    __syncthreads();
    for (int e = pbeg + t; e < pend; e += 256)
        atomicAdd(&cnt[(int)(pairs[e] >> 24)], 1);
    __syncthreads();
    int v = cnt[t];
    cur[t] = v;
    __syncthreads();
    for (int off = 1; off < 256; off <<= 1) {
        int x = (t >= off) ? cur[t - off] : 0;
        __syncthreads();
        cur[t] += x;
        __syncthreads();
    }
    int excl = cur[t] - v;
    int node = node0 + t;
    if (node < NODES) row_ptr[node] = pbeg + excl;
    cur[t] = excl;
    __syncthreads();
    if (n <= LMAX) {
        for (int e = pbeg + t; e < pend; e += 256) {
            unsigned p = pairs[e];
            int pos = atomicAdd(&cur[(int)(p >> 24)], 1);
            stage[pos] = (int)(p & 0xFFFFFFu);
        }
        __syncthreads();
        for (int i = t; i < n; i += 256) src_sorted[pbeg + i] = stage[i];
    } else {
        for (int e = pbeg + t; e < pend; e += 256) {
            unsigned p = pairs[e];
            int pos = atomicAdd(&cur[(int)(p >> 24)], 1);
            src_sorted[pbeg + pos] = (int)(p & 0xFFFFFFu);
        }
    }
}

// ---------------- Mean aggregation, fp8 gather ----------------
// R8-proven structure: 16-lane group per node (4 nodes/wave), shfl-broadcast
// indices, 16 row-gathers in flight, zero-pad row for tails, no cross-lane
// reduce (each lane owns its 8 features across all edges). R12 addition:
// software-pipelined srcs load (next chunk's indices issued before current
// chunk's converts — hides one srcs round-trip for degree>16 nodes).
// [XCD-slicing falsified twice: R11 traffic 8x (line sharing), R12
// latency-bound (per-node fixed costs x8). Do not revisit.]

__global__ __launch_bounds__(256) void agg128_fp8(
    const unsigned char* __restrict__ xq, const int* __restrict__ row_ptr,
    const int* __restrict__ srcs, unsigned short* __restrict__ out) {
    int wave = (blockIdx.x * 256 + threadIdx.x) >> 6;
    int lane = threadIdx.x & 63;
    int sl = lane & 15;
    int n = wave * 4 + (lane >> 4);
    if (n >= NODES) return;
    int beg = row_ptr[n], end = row_ptr[n + 1];
    int gb = lane & 48;  // group base lane (g*16)

    f32x2 A0[4], A1[4];
#pragma unroll
    for (int i = 0; i < 4; ++i) { A0[i] = {0.f, 0.f}; A1[i] = {0.f, 0.f}; }

    const unsigned char* xs = xq + sl * 8;
    int sv = (beg + sl < end) ? srcs[beg + sl] : NODES;  // NODES = zero pad row
    for (int base = beg; base < end; base += 16) {
        // prefetch next chunk's srcs index (in flight during converts)
        int nidx = base + 16 + sl;
        int nsv = (nidx < end) ? srcs[nidx] : NODES;
        uint2 vv[8], ww[8];
#pragma unroll
        for (int j = 0; j < 8; ++j) {
            int s = __shfl(sv, gb + j, 64);
            vv[j] = *reinterpret_cast<const uint2*>(xs + (size_t)s * 128);
        }
#pragma unroll
        for (int j = 0; j < 8; ++j) {
            int s = __shfl(sv, gb + 8 + j, 64);
            ww[j] = *reinterpret_cast<const uint2*>(xs + (size_t)s * 128);
        }
#pragma unroll
        for (int j = 0; j < 8; ++j) addpk8((j & 1) ? A1 : A0, vv[j]);
#pragma unroll
        for (int j = 0; j < 8; ++j) addpk8((j & 1) ? A0 : A1, ww[j]);
        sv = nsv;
    }

    float inv = 1.0f / fmaxf((float)(end - beg), 1.0f);
    f32x2 iv = {inv, inv};
    f32x2 z = {0.f, 0.f};
    f32x2 r0 = pkfma(pkadd(A0[0], A1[0]), iv, z);
    f32x2 r1 = pkfma(pkadd(A0[1], A1[1]), iv, z);
    f32x2 r2 = pkfma(pkadd(A0[2], A1[2]), iv, z);
    f32x2 r3 = pkfma(pkadd(A0[3], A1[3]), iv, z);
    uint4 o;
    o.x = cvt2bf(r0[0], r0[1]);
    o.y = cvt2bf(r1[0], r1[1]);
    o.z = cvt2bf(r2[0], r2[1]);
    o.w = cvt2bf(r3[0], r3[1]);
    *reinterpret_cast<uint4*>(out + (size_t)n * 128 + sl * 8) = o;
}

// agg64: group-per-node, 8-lane groups, 16-edge pipeline (R8 version).
__global__ __launch_bounds__(256) void agg64_add8(
    const unsigned char* __restrict__ xq, const int* __restrict__ row_ptr,
    const int* __restrict__ srcs, float* __restrict__ out) {
    int wave = (blockIdx.x * 256 + threadIdx.x) >> 6;
    int lane = threadIdx.x & 63;
    int sl = lane & 7;
    int n = wave * 8 + (lane >> 3);
    if (n >= NODES) return;
    int beg = row_ptr[n], end = row_ptr[n + 1];
    int gb = lane & 56;  // group base lane (g*8)

    f32x2 A0[4], A1[4];
#pragma unroll
    for (int i = 0; i < 4; ++i) { A0[i] = {0.f, 0.f}; A1[i] = {0.f, 0.f}; }

    const unsigned char* xs = xq + sl * 8;
    for (int base = beg; base < end; base += 16) {
        int i0 = base + sl, i1 = base + 8 + sl;
        int sv0 = (i0 < end) ? srcs[i0] : NODES;  // zero pad row
        int sv1 = (i1 < end) ? srcs[i1] : NODES;
        uint2 vv[16];
#pragma unroll
        for (int j = 0; j < 8; ++j) {
            int s = __shfl(sv0, gb + j, 64);
            vv[j] = *reinterpret_cast<const uint2*>(xs + (size_t)s * 64);
        }
#pragma unroll
        for (int j = 0; j < 8; ++j) {
            int s = __shfl(sv1, gb + j, 64);
            vv[8 + j] = *reinterpret_cast<const uint2*>(xs + (size_t)s * 64);
        }
#pragma unroll
        for (int j = 0; j < 16; ++j) addpk8((j & 1) ? A1 : A0, vv[j]);
    }

    float inv = 1.0f / fmaxf((float)(end - beg), 1.0f);
    f32x2 iv = {inv, inv};
    float* op = out + (size_t)n * 64 + sl * 8;
    f32x2 r0 = *reinterpret_cast<f32x2*>(op);
    f32x2 r1 = *reinterpret_cast<f32x2*>(op + 2);
    f32x2 r2 = *reinterpret_cast<f32x2*>(op + 4);
    f32x2 r3 = *reinterpret_cast<f32x2*>(op + 6);
    r0 = pkfma(pkadd(A0[0], A1[0]), iv, r0);
    r1 = pkfma(pkadd(A0[1], A1[1]), iv, r1);
    r2 = pkfma(pkadd(A0[2], A1[2]), iv, r2);
    r3 = pkfma(pkadd(A0[3], A1[3]), iv, r3);
    *reinterpret_cast<f32x2*>(op) = r0;
    *reinterpret_cast<f32x2*>(op + 2) = r1;
    *reinterpret_cast<f32x2*>(op + 4) = r2;
    *reinterpret_cast<f32x2*>(op + 6) = r3;
}

// ---------------- Fused MLP v6: 64-row chunks, wave-disjoint A ----

__global__ __launch_bounds__(256, 2) void fused_mlp(
    const unsigned short* __restrict__ featb, const unsigned short* __restrict__ agg,
    const unsigned short* __restrict__ Wt1s, const unsigned short* __restrict__ Wt1n,
    const float* __restrict__ b1, const unsigned short* __restrict__ Wt2s,
    const unsigned short* __restrict__ Wt2n, const float* __restrict__ b2,
    unsigned char* __restrict__ x1h8, float* __restrict__ outp) {
    __shared__ __align__(16) unsigned short w1t[32768];    // 64 KB, swizzled
    __shared__ __align__(16) unsigned short x1t[64 * 128]; // 16 KB, swizzled
    int wid = threadIdx.x >> 6, lane = threadIdx.x & 63;
    int l15 = lane & 15, quad = lane >> 4;

    // stage W1 -> LDS with 16B-slot swizzle
    {
        const uint4* gs = reinterpret_cast<const uint4*>(Wt1s);
        const uint4* gn = reinterpret_cast<const uint4*>(Wt1n);
        uint4* ls = reinterpret_cast<uint4*>(w1t);
        uint4* ln = ls + 2048;
#pragma unroll
        for (int i = 0; i < 8; ++i) {
            int g = threadIdx.x + i * 256;
            int sw = (g & ~15) | ((g & 15) ^ ((g >> 4) & 7));
            ls[sw] = gs[g];
            ln[sw] = gn[g];
        }
    }

    // B2 strips pinned in registers (8 frags, volatile asm)
    int col2 = wid * 16 + l15;
    bf16x8 B2s[4], B2n[4];
#pragma unroll
    for (int k = 0; k < 4; ++k) {
        B2s[k] = gl16(Wt2s + (size_t)col2 * 128 + k * 32 + quad * 8);
        B2n[k] = gl16(Wt2n + (size_t)col2 * 128 + k * 32 + quad * 8);
    }
    float bv2 = b2[col2];
    float bv1[8];
#pragma unroll
    for (int nt = 0; nt < 8; ++nt) bv1[nt] = b1[nt * 16 + l15];

    // per-wave disjoint 16-row A slice
    auto loadA = [&](int cc, bf16x8 (&Afd)[4], bf16x8 (&Aad)[4]) {
        int r = cc * 64 + wid * 16 + l15;
        if (r >= NODES) r = NODES - 1;  // tail clamp (stores guarded)
        const unsigned short* fp = featb + (size_t)r * 128 + quad * 8;
        const unsigned short* ap = agg + (size_t)r * 128 + quad * 8;
#pragma unroll
        for (int k = 0; k < 4; ++k) {
            Afd[k] = *reinterpret_cast<const bf16x8*>(fp + k * 32);
            Aad[k] = *reinterpret_cast<const bf16x8*>(ap + k * 32);
        }
    };

    bf16x8 Af[4], Aa[4];
    int c = blockIdx.x;
    if (c < NCH64) loadA(c, Af, Aa);

    // drain pinned B2 loads; fence; W1 visible (rule #18 ordering)
    asm volatile("s_waitcnt vmcnt(0)" ::: "memory");
    __builtin_amdgcn_sched_barrier(0);
    __syncthreads();

    int swz = l15 & 7;  // W1 read swizzle key (col&7 = l15&7)

    for (; c < NCH64; c += MLPGRID) {
        int rbase = c * 64;
        int cn = c + MLPGRID;

        // ---- phase 1: my 16 rows x all 128 W1 cols ----
        f32x4 acc[8];
#pragma unroll
        for (int nt = 0; nt < 8; ++nt) acc[nt] = {0.f, 0.f, 0.f, 0.f};
#pragma unroll
        for (int k = 0; k < 4; ++k) {
            int so = ((k * 4 + quad) ^ swz) << 3;  // swizzled 16B slot, in shorts
#pragma unroll
            for (int nt = 0; nt < 8; ++nt) {
                const unsigned short* wb = w1t + (size_t)(nt * 16 + l15) * 128;
                bf16x8 b1s = *reinterpret_cast<const bf16x8*>(wb + so);
                bf16x8 b1n = *reinterpret_cast<const bf16x8*>(wb + 16384 + so);
                acc[nt] = __builtin_amdgcn_mfma_f32_16x16x32_bf16(Af[k], b1s, acc[nt], 0, 0, 0);
                acc[nt] = __builtin_amdgcn_mfma_f32_16x16x32_bf16(Aa[k], b1n, acc[nt], 0, 0, 0);
            }
        }

        // prefetch next chunk's A (overlaps epilogue + phase 2)
        bf16x8 Pf[4], Pa[4];
        if (cn < NCH64) loadA(cn, Pf, Pa);

        // ---- epilogue: relu+bias -> x1t (XOR slot swizzle) ----
#pragma unroll
        for (int nt = 0; nt < 8; ++nt)
#pragma unroll
            for (int rr = 0; rr < 4; ++rr) {
                float v = fmaxf(acc[nt][rr] + bv1[nt], 0.f);
                int row = wid * 16 + quad * 4 + rr;        // 0..63
                int col = nt * 16 + l15;                   // 0..127
                int slot = (col >> 3) ^ (row & 7);         // XOR low 3 bits
                x1t[row * 128 + slot * 8 + (col & 7)] = f2b(v);
            }
        __syncthreads();

        // ---- phase 2: my 16 cols x all 64 rows ----
        f32x4 a2s[4], a2n[4];
#pragma unroll
        for (int mt = 0; mt < 4; ++mt) { a2s[mt] = {0.f, 0.f, 0.f, 0.f}; a2n[mt] = {0.f, 0.f, 0.f, 0.f}; }
#pragma unroll
        for (int k = 0; k < 4; ++k)
#pragma unroll
            for (int mt = 0; mt < 4; ++mt) {
                int row = mt * 16 + l15;
                int slot = (k * 4 + quad) ^ (row & 7);
                bf16x8 a = *reinterpret_cast<const bf16x8*>(x1t + row * 128 + slot * 8);
                a2s[mt] = __builtin_amdgcn_mfma_f32_16x16x32_bf16(a, B2s[k], a2s[mt], 0, 0, 0);
                a2n[mt] = __builtin_amdgcn_mfma_f32_16x16x32_bf16(a, B2n[k], a2n[mt], 0, 0, 0);
            }
        __syncthreads();  // x1t consumed; next iteration may overwrite

        // ---- stores ----
#pragma unroll
        for (int mt = 0; mt < 4; ++mt)
#pragma unroll
            for (int rr = 0; rr < 4; ++rr) {
                int row = rbase + mt * 16 + quad * 4 + rr;
                if (row < NODES) {
                    float vn = a2n[mt][rr];
                    int pk = __builtin_amdgcn_cvt_pk_fp8_f32(vn, vn, 0, false);
                    x1h8[(size_t)row * 64 + col2] = (unsigned char)(pk & 0xFF);
                    outp[(size_t)row * 64 + col2] = a2s[mt][rr] + bv2;
                }
            }

        if (cn < NCH64) {
#pragma unroll
            for (int k = 0; k < 4; ++k) {
                Af[k] = Pf[k];
                Aa[k] = Pa[k];
            }
        }
    }
}

// ---------------- launch ----------------

extern "C" void kernel_launch(void* const* d_in, const int* in_sizes, int n_in,
                              void* d_out, int out_size, void* d_ws, size_t ws_size,
                              hipStream_t stream) {
    const float* features = (const float*)d_in[0];
    const int* esrc = (const int*)d_in[1];
    const int* edst = (const int*)d_in[2];
    const float* W1s = (const float*)d_in[3];
    const float* W1n = (const float*)d_in[4];
    const float* b1  = (const float*)d_in[5];
    const float* W2s = (const float*)d_in[6];
    const float* W2n = (const float*)d_in[7];
    const float* b2  = (const float*)d_in[8];
    float* out = (float*)d_out;

    char* ws = (char*)d_ws;
    size_t off = 0;
    auto alloc = [&](size_t bytes) {
        void* p = ws + off;
        off += (bytes + 255) & ~(size_t)255;
        return p;
    };
    int* bucket_cnt = (int*)alloc(512 * 4);
    int* bucket_off = (int*)alloc(512 * 4);
    int* gcursor    = (int*)alloc(512 * 4);
    int* row_ptr    = (int*)alloc((size_t)(NODES + 1) * 4);
    int* src_sorted = (int*)alloc((size_t)EDGES * 4);
    unsigned* pairs = (unsigned*)alloc((size_t)EDGES * 4);
    unsigned short* featb = (unsigned short*)alloc((size_t)NODES * 128 * 2);
    unsigned char*  feat8 = (unsigned char*)alloc((size_t)(NODES + 1) * 128);  // +zero pad row
    unsigned short* agg1  = (unsigned short*)alloc((size_t)NODES * 128 * 2);
    unsigned char*  x1h8  = (unsigned char*)alloc((size_t)(NODES + 1) * 64);   // +zero pad row
    unsigned short* Wt1s  = (unsigned short*)alloc(16384 * 2);
    unsigned short* Wt1n  = (unsigned short*)alloc(16384 * 2);
    unsigned short* Wt2s  = (unsigned short*)alloc(8192 * 2);
    unsigned short* Wt2n  = (unsigned short*)alloc(8192 * 2);

    // zero pad rows + bucket counters
    hipMemsetAsync(bucket_cnt, 0, 512 * 4, stream);
    hipMemsetAsync(feat8 + (size_t)NODES * 128, 0, 128, stream);
    hipMemsetAsync(x1h8 + (size_t)NODES * 64, 0, 64, stream);

    // fused conversions + coarse histogram
    conv_hist<<<CONVB + (EDGES + 16383) / 16384, 256, 0, stream>>>(
        features, featb, feat8, NODES * 128 / 4, W1s, W1n, W2s, W2n,
        Wt1s, Wt1n, Wt2s, Wt2n, edst, bucket_cnt);

    bscan_kernel<<<1, 512, 0, stream>>>(bucket_cnt, bucket_off, gcursor, row_ptr);
    binscat_kernel<<<(EDGES + CHUNK - 1) / CHUNK, 256, 0, stream>>>(esrc, edst, gcursor, pairs);
    localsort_kernel<<<NBUCK, 256, 0, stream>>>(pairs, bucket_off, row_ptr, src_sorted);

    // layer 1 aggregation (fp8 gather -> bf16 agg matrix); 4 nodes/wave
    agg128_fp8<<<(NODES / 4 * 64 + 255) / 256, 256, 0, stream>>>(feat8, row_ptr, src_sorted, agg1);

    // fused MLP v6: 64-row chunks, wave-disjoint A, W1 in LDS
    fused_mlp<<<MLPGRID, 256, 0, stream>>>(featb, agg1, Wt1s, Wt1n, b1, Wt2s, Wt2n, b2, x1h8, out);

    // out += mean-neigh(x1h); 8 nodes/wave, 16-deep
    agg64_add8<<<(NODES / 8 * 64 + 255) / 256, 256, 0, stream>>>(x1h8, row_ptr, src_sorted, out);
}

// Round 14
// 237.410 us; speedup vs baseline: 1.6076x; 1.0062x over previous
//
#include <hip/hip_runtime.h>

#define NODES 100000
#define EDGES 1600000
#define BSH 8
#define NBUCK ((NODES + 255) >> BSH)   // 391
#define CHUNK 4096
#define LMAX 8192
#define NCH64 ((NODES + 63) / 64)      // 1563 (tail clamped)
#define CONVB 12500                    // blocks for conv part of conv_hist
#define MLPGRID 512                    // 2 blocks/CU (LDS = 80 KB exactly)
// IN_F = HID_F = 128, OUT_F = 64

using bf16x8 = __attribute__((ext_vector_type(8))) short;
using f32x4  = __attribute__((ext_vector_type(4))) float;
using f32x2  = __attribute__((ext_vector_type(2))) float;

__device__ __forceinline__ unsigned short f2b(float f) {
    unsigned u = __builtin_bit_cast(unsigned, f);
    unsigned r = (u + 0x7FFFu + ((u >> 16) & 1u)) >> 16;
    return (unsigned short)r;
}

// ---- packed f32 helpers (CDNA VOP3P; dual-pump FP32) ----
__device__ __forceinline__ f32x2 pkadd(f32x2 a, f32x2 b) {
    f32x2 d;
    asm("v_pk_add_f32 %0, %1, %2" : "=v"(d) : "v"(a), "v"(b));
    return d;
}
__device__ __forceinline__ f32x2 pkfma(f32x2 a, f32x2 b, f32x2 c) {
    f32x2 d;
    asm("v_pk_fma_f32 %0, %1, %2, %3" : "=v"(d) : "v"(a), "v"(b), "v"(c));
    return d;
}
__device__ __forceinline__ unsigned cvt2bf(float lo, float hi) {
    unsigned r;
    asm("v_cvt_pk_bf16_f32 %0, %1, %2" : "=v"(r) : "v"(lo), "v"(hi));
    return r;
}

// pinned 16B global load (volatile: cannot be sunk/rematerialized)
__device__ __forceinline__ bf16x8 gl16(const unsigned short* p) {
    bf16x8 r;
    asm volatile("global_load_dwordx4 %0, %1, off" : "=&v"(r) : "v"(p));
    return r;
}

// unpack 8 fp8 (uint2) and accumulate into 4 packed-f32 accumulators
__device__ __forceinline__ void addpk8(f32x2* a, uint2 v) {
    a[0] = pkadd(a[0], __builtin_amdgcn_cvt_pk_f32_fp8((int)v.x, false));
    a[1] = pkadd(a[1], __builtin_amdgcn_cvt_pk_f32_fp8((int)v.x, true));
    a[2] = pkadd(a[2], __builtin_amdgcn_cvt_pk_f32_fp8((int)v.y, false));
    a[3] = pkadd(a[3], __builtin_amdgcn_cvt_pk_f32_fp8((int)v.y, true));
}

// ---------------- fused conversions + coarse histogram ----------------

__global__ __launch_bounds__(256) void conv_hist(
    const float* __restrict__ in, unsigned short* __restrict__ outb,
    unsigned char* __restrict__ outq, int n4,
    const float* __restrict__ W1s, const float* __restrict__ W1n,
    const float* __restrict__ W2s, const float* __restrict__ W2n,
    unsigned short* __restrict__ Wt1s, unsigned short* __restrict__ Wt1n,
    unsigned short* __restrict__ Wt2s, unsigned short* __restrict__ Wt2n,
    const int* __restrict__ dst, int* __restrict__ bucket_cnt) {
    int t = threadIdx.x;
    if (blockIdx.x < CONVB) {
        int i = blockIdx.x * 256 + t;
        if (i < n4) {
            float4 v = reinterpret_cast<const float4*>(in)[i];
            uint2 o;
            o.x = (unsigned)f2b(v.x) | ((unsigned)f2b(v.y) << 16);
            o.y = (unsigned)f2b(v.z) | ((unsigned)f2b(v.w) << 16);
            reinterpret_cast<uint2*>(outb)[i] = o;
            int pk = __builtin_amdgcn_cvt_pk_fp8_f32(v.x, v.y, 0, false);
            pk = __builtin_amdgcn_cvt_pk_fp8_f32(v.z, v.w, pk, true);
            reinterpret_cast<unsigned*>(outq)[i] = (unsigned)pk;
        }
        if (i < 16384) {
            int k = i >> 7, n = i & 127;
            Wt1s[n * 128 + k] = f2b(W1s[i]);
            Wt1n[n * 128 + k] = f2b(W1n[i]);
        }
        if (i < 8192) {
            int k = i >> 6, n = i & 63;
            Wt2s[n * 128 + k] = f2b(W2s[i]);
            Wt2n[n * 128 + k] = f2b(W2n[i]);
        }
        return;
    }
    // ---- bhist part ----
    __shared__ int lcnt[512];
    lcnt[t] = 0; lcnt[t + 256] = 0;
    __syncthreads();
    int base = (blockIdx.x - CONVB) * 16384;
    int n = EDGES - base;
    if (n > 16384) n = 16384;
    const int4* d4 = reinterpret_cast<const int4*>(dst + base);
    for (int i = t; i < (n >> 2); i += 256) {
        int4 d = d4[i];
        atomicAdd(&lcnt[d.x >> BSH], 1);
        atomicAdd(&lcnt[d.y >> BSH], 1);
        atomicAdd(&lcnt[d.z >> BSH], 1);
        atomicAdd(&lcnt[d.w >> BSH], 1);
    }
    for (int i = (n & ~3) + t; i < n; i += 256) atomicAdd(&lcnt[dst[base + i] >> BSH], 1);
    __syncthreads();
    if (lcnt[t]) atomicAdd(&bucket_cnt[t], lcnt[t]);
    if (lcnt[t + 256]) atomicAdd(&bucket_cnt[t + 256], lcnt[t + 256]);
}

__global__ void bscan_kernel(const int* __restrict__ bucket_cnt, int* __restrict__ bucket_off,
                             int* __restrict__ gcursor, int* __restrict__ row_ptr) {
    __shared__ int sh[512];
    int t = threadIdx.x;
    int v = (t < NBUCK) ? bucket_cnt[t] : 0;
    sh[t] = v;
    __syncthreads();
    for (int off = 1; off < 512; off <<= 1) {
        int x = (t >= off) ? sh[t - off] : 0;
        __syncthreads();
        sh[t] += x;
        __syncthreads();
    }
    int excl = sh[t] - v;
    if (t < NBUCK) { bucket_off[t] = excl; gcursor[t] = excl; }
    if (t == NBUCK) bucket_off[t] = EDGES;
    if (t == 0) row_ptr[NODES] = EDGES;
}

// Bin edges by coarse bucket; write packed (dst&255)<<24|src runs.
__global__ __launch_bounds__(256) void binscat_kernel(
    const int* __restrict__ src, const int* __restrict__ dst,
    int* __restrict__ gcursor, unsigned* __restrict__ pairs) {
    __shared__ int cnt[512];
    __shared__ int scn[512];
    __shared__ int gbs[512];
    __shared__ int cur[512];
    __shared__ uint2 stage[CHUNK];
    int t = threadIdx.x;
    int base = blockIdx.x * CHUNK;
    int n = EDGES - base;
    if (n > CHUNK) n = CHUNK;

    cnt[t] = 0; cnt[t + 256] = 0;
    __syncthreads();

    uint2 my[16];
#pragma unroll
    for (int i = 0; i < 16; ++i) {
        int idx = t + i * 256;
        if (idx < n) {
            int d = dst[base + idx];
            int s = src[base + idx];
            my[i] = make_uint2((unsigned)d, (unsigned)s);
            atomicAdd(&cnt[d >> BSH], 1);
        } else {
            my[i] = make_uint2(0xFFFFFFFFu, 0);
        }
    }
    __syncthreads();
    scn[t] = cnt[t]; scn[t + 256] = cnt[t + 256];
    __syncthreads();
    for (int off = 1; off < 512; off <<= 1) {
        int a0 = (t >= off) ? scn[t - off] : 0;
        int a1 = (t + 256 >= off) ? scn[t + 256 - off] : 0;
        __syncthreads();
        scn[t] += a0; scn[t + 256] += a1;
        __syncthreads();
    }
    cur[t] = scn[t] - cnt[t];
    cur[t + 256] = scn[t + 256] - cnt[t + 256];
    __syncthreads();
#pragma unroll
    for (int i = 0; i < 16; ++i) {
        if (my[i].x != 0xFFFFFFFFu) {
            int b = (int)(my[i].x >> BSH);
            int p = atomicAdd(&cur[b], 1);
            stage[p] = my[i];
        }
    }
    for (int b2 = t; b2 < 512; b2 += 256) {
        int c = cnt[b2];
        gbs[b2] = (c > 0 && b2 < NBUCK) ? atomicAdd(&gcursor[b2], c) : 0;
    }
    __syncthreads();
    for (int idx = t; idx < n; idx += 256) {
        uint2 p = stage[idx];
        int b = (int)(p.x >> BSH);
        int excl = scn[b] - cnt[b];
        pairs[gbs[b] + idx - excl] = ((p.x & 255u) << 24) | p.y;
    }
}

__global__ __launch_bounds__(256) void localsort_kernel(
    const unsigned* __restrict__ pairs, const int* __restrict__ bucket_off,
    int* __restrict__ row_ptr, int* __restrict__ src_sorted) {
    __shared__ int cnt[256];
    __shared__ int cur[256];
    __shared__ int stage[LMAX];
    int b = blockIdx.x;
    int t = threadIdx.x;
    int node0 = b << BSH;
    int pbeg = bucket_off[b], pend = bucket_off[b + 1];
    int n = pend - pbeg;
    cnt[t] = 0;
    __syncthreads();
    for (int e = pbeg + t; e < pend; e += 256)
        atomicAdd(&cnt[(int)(pairs[e] >> 24)], 1);
    __syncthreads();
    int v = cnt[t];
    cur[t] = v;
    __syncthreads();
    for (int off = 1; off < 256; off <<= 1) {
        int x = (t >= off) ? cur[t - off] : 0;
        __syncthreads();
        cur[t] += x;
        __syncthreads();
    }
    int excl = cur[t] - v;
    int node = node0 + t;
    if (node < NODES) row_ptr[node] = pbeg + excl;
    cur[t] = excl;
    __syncthreads();
    if (n <= LMAX) {
        for (int e = pbeg + t; e < pend; e += 256) {
            unsigned p = pairs[e];
            int pos = atomicAdd(&cur[(int)(p >> 24)], 1);
            stage[pos] = (int)(p & 0xFFFFFFu);
        }
        __syncthreads();
        for (int i = t; i < n; i += 256) src_sorted[pbeg + i] = stage[i];
    } else {
        for (int e = pbeg + t; e < pend; e += 256) {
            unsigned p = pairs[e];
            int pos = atomicAdd(&cur[(int)(p >> 24)], 1);
            src_sorted[pbeg + pos] = (int)(p & 0xFFFFFFu);
        }
    }
}

// ---------------- Mean aggregation, fp8 gather ----------------
// v8: R8 structure deepened to 32 gathers in flight. Two 16-edge chunks'
// indices broadcast (sv0, sv1), all 32 row-gathers issued back-to-back,
// then all 32 converted. R11 accidentally showed the L2-miss fabric
// sustains 3.7 TB/s with enough parallel misses; R8's 16-deep achieved
// only 2.25. Zero-pad row masks all tails.
// [XCD-slicing falsified twice: R11 traffic 8x (line sharing), R12
// latency-bound (per-node fixed costs x8). Do not revisit.]

__global__ __launch_bounds__(256) void agg128_fp8(
    const unsigned char* __restrict__ xq, const int* __restrict__ row_ptr,
    const int* __restrict__ srcs, unsigned short* __restrict__ out) {
    int wave = (blockIdx.x * 256 + threadIdx.x) >> 6;
    int lane = threadIdx.x & 63;
    int sl = lane & 15;
    int n = wave * 4 + (lane >> 4);
    if (n >= NODES) return;
    int beg = row_ptr[n], end = row_ptr[n + 1];
    int gb = lane & 48;  // group base lane (g*16)

    f32x2 A0[4], A1[4];
#pragma unroll
    for (int i = 0; i < 4; ++i) { A0[i] = {0.f, 0.f}; A1[i] = {0.f, 0.f}; }

    const unsigned char* xs = xq + sl * 8;
    int sv0 = (beg + sl < end) ? srcs[beg + sl] : NODES;          // pad row
    int sv1 = (beg + 16 + sl < end) ? srcs[beg + 16 + sl] : NODES;
    for (int base = beg; base < end; base += 32) {
        // prefetch next pair's indices (in flight during converts)
        int ni0 = base + 32 + sl, ni1 = base + 48 + sl;
        int nv0 = (ni0 < end) ? srcs[ni0] : NODES;
        int nv1 = (ni1 < end) ? srcs[ni1] : NODES;
        uint2 vv[16], ww[16];
#pragma unroll
        for (int j = 0; j < 16; ++j) {
            int s = __shfl(sv0, gb + j, 64);
            vv[j] = *reinterpret_cast<const uint2*>(xs + (size_t)s * 128);
        }
#pragma unroll
        for (int j = 0; j < 16; ++j) {
            int s = __shfl(sv1, gb + j, 64);
            ww[j] = *reinterpret_cast<const uint2*>(xs + (size_t)s * 128);
        }
#pragma unroll
        for (int j = 0; j < 16; ++j) addpk8((j & 1) ? A1 : A0, vv[j]);
#pragma unroll
        for (int j = 0; j < 16; ++j) addpk8((j & 1) ? A0 : A1, ww[j]);
        sv0 = nv0;
        sv1 = nv1;
    }

    float inv = 1.0f / fmaxf((float)(end - beg), 1.0f);
    f32x2 iv = {inv, inv};
    f32x2 z = {0.f, 0.f};
    f32x2 r0 = pkfma(pkadd(A0[0], A1[0]), iv, z);
    f32x2 r1 = pkfma(pkadd(A0[1], A1[1]), iv, z);
    f32x2 r2 = pkfma(pkadd(A0[2], A1[2]), iv, z);
    f32x2 r3 = pkfma(pkadd(A0[3], A1[3]), iv, z);
    uint4 o;
    o.x = cvt2bf(r0[0], r0[1]);
    o.y = cvt2bf(r1[0], r1[1]);
    o.z = cvt2bf(r2[0], r2[1]);
    o.w = cvt2bf(r3[0], r3[1]);
    *reinterpret_cast<uint4*>(out + (size_t)n * 128 + sl * 8) = o;
}

// agg64: group-per-node, 8-lane groups; v3: 32-edge pipeline (four 8-wide
// srcs index fetches, 32 gathers in flight).
__global__ __launch_bounds__(256) void agg64_add8(
    const unsigned char* __restrict__ xq, const int* __restrict__ row_ptr,
    const int* __restrict__ srcs, float* __restrict__ out) {
    int wave = (blockIdx.x * 256 + threadIdx.x) >> 6;
    int lane = threadIdx.x & 63;
    int sl = lane & 7;
    int n = wave * 8 + (lane >> 3);
    if (n >= NODES) return;
    int beg = row_ptr[n], end = row_ptr[n + 1];
    int gb = lane & 56;  // group base lane (g*8)

    f32x2 A0[4], A1[4];
#pragma unroll
    for (int i = 0; i < 4; ++i) { A0[i] = {0.f, 0.f}; A1[i] = {0.f, 0.f}; }

    const unsigned char* xs = xq + sl * 8;
    for (int base = beg; base < end; base += 32) {
        int i0 = base + sl, i1 = base + 8 + sl, i2 = base + 16 + sl, i3 = base + 24 + sl;
        int sv0 = (i0 < end) ? srcs[i0] : NODES;  // zero pad row
        int sv1 = (i1 < end) ? srcs[i1] : NODES;
        int sv2 = (i2 < end) ? srcs[i2] : NODES;
        int sv3 = (i3 < end) ? srcs[i3] : NODES;
        uint2 vv[32];
#pragma unroll
        for (int j = 0; j < 8; ++j) {
            int s = __shfl(sv0, gb + j, 64);
            vv[j] = *reinterpret_cast<const uint2*>(xs + (size_t)s * 64);
        }
#pragma unroll
        for (int j = 0; j < 8; ++j) {
            int s = __shfl(sv1, gb + j, 64);
            vv[8 + j] = *reinterpret_cast<const uint2*>(xs + (size_t)s * 64);
        }
#pragma unroll
        for (int j = 0; j < 8; ++j) {
            int s = __shfl(sv2, gb + j, 64);
            vv[16 + j] = *reinterpret_cast<const uint2*>(xs + (size_t)s * 64);
        }
#pragma unroll
        for (int j = 0; j < 8; ++j) {
            int s = __shfl(sv3, gb + j, 64);
            vv[24 + j] = *reinterpret_cast<const uint2*>(xs + (size_t)s * 64);
        }
#pragma unroll
        for (int j = 0; j < 32; ++j) addpk8((j & 1) ? A1 : A0, vv[j]);
    }

    float inv = 1.0f / fmaxf((float)(end - beg), 1.0f);
    f32x2 iv = {inv, inv};
    float* op = out + (size_t)n * 64 + sl * 8;
    f32x2 r0 = *reinterpret_cast<f32x2*>(op);
    f32x2 r1 = *reinterpret_cast<f32x2*>(op + 2);
    f32x2 r2 = *reinterpret_cast<f32x2*>(op + 4);
    f32x2 r3 = *reinterpret_cast<f32x2*>(op + 6);
    r0 = pkfma(pkadd(A0[0], A1[0]), iv, r0);
    r1 = pkfma(pkadd(A0[1], A1[1]), iv, r1);
    r2 = pkfma(pkadd(A0[2], A1[2]), iv, r2);
    r3 = pkfma(pkadd(A0[3], A1[3]), iv, r3);
    *reinterpret_cast<f32x2*>(op) = r0;
    *reinterpret_cast<f32x2*>(op + 2) = r1;
    *reinterpret_cast<f32x2*>(op + 4) = r2;
    *reinterpret_cast<f32x2*>(op + 6) = r3;
}

// ---------------- Fused MLP v6: 64-row chunks, wave-disjoint A ----

__global__ __launch_bounds__(256, 2) void fused_mlp(
    const unsigned short* __restrict__ featb, const unsigned short* __restrict__ agg,
    const unsigned short* __restrict__ Wt1s, const unsigned short* __restrict__ Wt1n,
    const float* __restrict__ b1, const unsigned short* __restrict__ Wt2s,
    const unsigned short* __restrict__ Wt2n, const float* __restrict__ b2,
    unsigned char* __restrict__ x1h8, float* __restrict__ outp) {
    __shared__ __align__(16) unsigned short w1t[32768];    // 64 KB, swizzled
    __shared__ __align__(16) unsigned short x1t[64 * 128]; // 16 KB, swizzled
    int wid = threadIdx.x >> 6, lane = threadIdx.x & 63;
    int l15 = lane & 15, quad = lane >> 4;

    // stage W1 -> LDS with 16B-slot swizzle
    {
        const uint4* gs = reinterpret_cast<const uint4*>(Wt1s);
        const uint4* gn = reinterpret_cast<const uint4*>(Wt1n);
        uint4* ls = reinterpret_cast<uint4*>(w1t);
        uint4* ln = ls + 2048;
#pragma unroll
        for (int i = 0; i < 8; ++i) {
            int g = threadIdx.x + i * 256;
            int sw = (g & ~15) | ((g & 15) ^ ((g >> 4) & 7));
            ls[sw] = gs[g];
            ln[sw] = gn[g];
        }
    }

    // B2 strips pinned in registers (8 frags, volatile asm)
    int col2 = wid * 16 + l15;
    bf16x8 B2s[4], B2n[4];
#pragma unroll
    for (int k = 0; k < 4; ++k) {
        B2s[k] = gl16(Wt2s + (size_t)col2 * 128 + k * 32 + quad * 8);
        B2n[k] = gl16(Wt2n + (size_t)col2 * 128 + k * 32 + quad * 8);
    }
    float bv2 = b2[col2];
    float bv1[8];
#pragma unroll
    for (int nt = 0; nt < 8; ++nt) bv1[nt] = b1[nt * 16 + l15];

    // per-wave disjoint 16-row A slice
    auto loadA = [&](int cc, bf16x8 (&Afd)[4], bf16x8 (&Aad)[4]) {
        int r = cc * 64 + wid * 16 + l15;
        if (r >= NODES) r = NODES - 1;  // tail clamp (stores guarded)
        const unsigned short* fp = featb + (size_t)r * 128 + quad * 8;
        const unsigned short* ap = agg + (size_t)r * 128 + quad * 8;
#pragma unroll
        for (int k = 0; k < 4; ++k) {
            Afd[k] = *reinterpret_cast<const bf16x8*>(fp + k * 32);
            Aad[k] = *reinterpret_cast<const bf16x8*>(ap + k * 32);
        }
    };

    bf16x8 Af[4], Aa[4];
    int c = blockIdx.x;
    if (c < NCH64) loadA(c, Af, Aa);

    // drain pinned B2 loads; fence; W1 visible (rule #18 ordering)
    asm volatile("s_waitcnt vmcnt(0)" ::: "memory");
    __builtin_amdgcn_sched_barrier(0);
    __syncthreads();

    int swz = l15 & 7;  // W1 read swizzle key (col&7 = l15&7)

    for (; c < NCH64; c += MLPGRID) {
        int rbase = c * 64;
        int cn = c + MLPGRID;

        // ---- phase 1: my 16 rows x all 128 W1 cols ----
        f32x4 acc[8];
#pragma unroll
        for (int nt = 0; nt < 8; ++nt) acc[nt] = {0.f, 0.f, 0.f, 0.f};
#pragma unroll
        for (int k = 0; k < 4; ++k) {
            int so = ((k * 4 + quad) ^ swz) << 3;  // swizzled 16B slot, in shorts
#pragma unroll
            for (int nt = 0; nt < 8; ++nt) {
                const unsigned short* wb = w1t + (size_t)(nt * 16 + l15) * 128;
                bf16x8 b1s = *reinterpret_cast<const bf16x8*>(wb + so);
                bf16x8 b1n = *reinterpret_cast<const bf16x8*>(wb + 16384 + so);
                acc[nt] = __builtin_amdgcn_mfma_f32_16x16x32_bf16(Af[k], b1s, acc[nt], 0, 0, 0);
                acc[nt] = __builtin_amdgcn_mfma_f32_16x16x32_bf16(Aa[k], b1n, acc[nt], 0, 0, 0);
            }
        }

        // prefetch next chunk's A (overlaps epilogue + phase 2)
        bf16x8 Pf[4], Pa[4];
        if (cn < NCH64) loadA(cn, Pf, Pa);

        // ---- epilogue: relu+bias -> x1t (XOR slot swizzle) ----
#pragma unroll
        for (int nt = 0; nt < 8; ++nt)
#pragma unroll
            for (int rr = 0; rr < 4; ++rr) {
                float v = fmaxf(acc[nt][rr] + bv1[nt], 0.f);
                int row = wid * 16 + quad * 4 + rr;        // 0..63
                int col = nt * 16 + l15;                   // 0..127
                int slot = (col >> 3) ^ (row & 7);         // XOR low 3 bits
                x1t[row * 128 + slot * 8 + (col & 7)] = f2b(v);
            }
        __syncthreads();

        // ---- phase 2: my 16 cols x all 64 rows ----
        f32x4 a2s[4], a2n[4];
#pragma unroll
        for (int mt = 0; mt < 4; ++mt) { a2s[mt] = {0.f, 0.f, 0.f, 0.f}; a2n[mt] = {0.f, 0.f, 0.f, 0.f}; }
#pragma unroll
        for (int k = 0; k < 4; ++k)
#pragma unroll
            for (int mt = 0; mt < 4; ++mt) {
                int row = mt * 16 + l15;
                int slot = (k * 4 + quad) ^ (row & 7);
                bf16x8 a = *reinterpret_cast<const bf16x8*>(x1t + row * 128 + slot * 8);
                a2s[mt] = __builtin_amdgcn_mfma_f32_16x16x32_bf16(a, B2s[k], a2s[mt], 0, 0, 0);
                a2n[mt] = __builtin_amdgcn_mfma_f32_16x16x32_bf16(a, B2n[k], a2n[mt], 0, 0, 0);
            }
        __syncthreads();  // x1t consumed; next iteration may overwrite

        // ---- stores ----
#pragma unroll
        for (int mt = 0; mt < 4; ++mt)
#pragma unroll
            for (int rr = 0; rr < 4; ++rr) {
                int row = rbase + mt * 16 + quad * 4 + rr;
                if (row < NODES) {
                    float vn = a2n[mt][rr];
                    int pk = __builtin_amdgcn_cvt_pk_fp8_f32(vn, vn, 0, false);
                    x1h8[(size_t)row * 64 + col2] = (unsigned char)(pk & 0xFF);
                    outp[(size_t)row * 64 + col2] = a2s[mt][rr] + bv2;
                }
            }

        if (cn < NCH64) {
#pragma unroll
            for (int k = 0; k < 4; ++k) {
                Af[k] = Pf[k];
                Aa[k] = Pa[k];
            }
        }
    }
}

// ---------------- launch ----------------

extern "C" void kernel_launch(void* const* d_in, const int* in_sizes, int n_in,
                              void* d_out, int out_size, void* d_ws, size_t ws_size,
                              hipStream_t stream) {
    const float* features = (const float*)d_in[0];
    const int* esrc = (const int*)d_in[1];
    const int* edst = (const int*)d_in[2];
    const float* W1s = (const float*)d_in[3];
    const float* W1n = (const float*)d_in[4];
    const float* b1  = (const float*)d_in[5];
    const float* W2s = (const float*)d_in[6];
    const float* W2n = (const float*)d_in[7];
    const float* b2  = (const float*)d_in[8];
    float* out = (float*)d_out;

    char* ws = (char*)d_ws;
    size_t off = 0;
    auto alloc = [&](size_t bytes) {
        void* p = ws + off;
        off += (bytes + 255) & ~(size_t)255;
        return p;
    };
    int* bucket_cnt = (int*)alloc(512 * 4);
    int* bucket_off = (int*)alloc(512 * 4);
    int* gcursor    = (int*)alloc(512 * 4);
    int* row_ptr    = (int*)alloc((size_t)(NODES + 1) * 4);
    int* src_sorted = (int*)alloc((size_t)EDGES * 4);
    unsigned* pairs = (unsigned*)alloc((size_t)EDGES * 4);
    unsigned short* featb = (unsigned short*)alloc((size_t)NODES * 128 * 2);
    unsigned char*  feat8 = (unsigned char*)alloc((size_t)(NODES + 1) * 128);  // +zero pad row
    unsigned short* agg1  = (unsigned short*)alloc((size_t)NODES * 128 * 2);
    unsigned char*  x1h8  = (unsigned char*)alloc((size_t)(NODES + 1) * 64);   // +zero pad row
    unsigned short* Wt1s  = (unsigned short*)alloc(16384 * 2);
    unsigned short* Wt1n  = (unsigned short*)alloc(16384 * 2);
    unsigned short* Wt2s  = (unsigned short*)alloc(8192 * 2);
    unsigned short* Wt2n  = (unsigned short*)alloc(8192 * 2);

    // zero pad rows + bucket counters
    hipMemsetAsync(bucket_cnt, 0, 512 * 4, stream);
    hipMemsetAsync(feat8 + (size_t)NODES * 128, 0, 128, stream);
    hipMemsetAsync(x1h8 + (size_t)NODES * 64, 0, 64, stream);

    // fused conversions + coarse histogram
    conv_hist<<<CONVB + (EDGES + 16383) / 16384, 256, 0, stream>>>(
        features, featb, feat8, NODES * 128 / 4, W1s, W1n, W2s, W2n,
        Wt1s, Wt1n, Wt2s, Wt2n, edst, bucket_cnt);

    bscan_kernel<<<1, 512, 0, stream>>>(bucket_cnt, bucket_off, gcursor, row_ptr);
    binscat_kernel<<<(EDGES + CHUNK - 1) / CHUNK, 256, 0, stream>>>(esrc, edst, gcursor, pairs);
    localsort_kernel<<<NBUCK, 256, 0, stream>>>(pairs, bucket_off, row_ptr, src_sorted);

    // layer 1 aggregation (fp8 gather -> bf16 agg matrix); 4 nodes/wave, 32-deep
    agg128_fp8<<<(NODES / 4 * 64 + 255) / 256, 256, 0, stream>>>(feat8, row_ptr, src_sorted, agg1);

    // fused MLP v6: 64-row chunks, wave-disjoint A, W1 in LDS
    fused_mlp<<<MLPGRID, 256, 0, stream>>>(featb, agg1, Wt1s, Wt1n, b1, Wt2s, Wt2n, b2, x1h8, out);

    // out += mean-neigh(x1h); 8 nodes/wave, 32-deep
    agg64_add8<<<(NODES / 8 * 64 + 255) / 256, 256, 0, stream>>>(x1h8, row_ptr, src_sorted, out);
}